// Round 1
// baseline (168.227 us; speedup 1.0000x reference)
//
#include <hip/hip_runtime.h>
#include <cstdint>
#include <cstddef>
#include <math.h>

#define SEQ    2048
#define NBATCH 4
#define DIN    1024
#define DH     64

typedef __attribute__((ext_vector_type(8))) short  short8;   // 8 x bf16 (4 VGPRs)
typedef __attribute__((ext_vector_type(4))) float  floatx4;  // MFMA C/D

#define MFMA16(a, b, c) __builtin_amdgcn_mfma_f32_16x16x32_bf16((a), (b), (c), 0, 0, 0)

__device__ __forceinline__ unsigned short f2bf(float x) {
  unsigned u = __float_as_uint(x);
  return (unsigned short)((u + 0x8000u) >> 16);   // round-half-up; values finite
}
__device__ __forceinline__ float bf2f(unsigned short h) {
  return __uint_as_float(((unsigned)h) << 16);
}

// ======================= host-side numpy RNG replication =======================
namespace nprng {

struct PCG64 {
  __uint128_t state, inc;
  bool has_uint32;
  uint32_t uinteger;
};

static inline void pcg_step(PCG64 &g) {
  const __uint128_t MULT =
      (((__uint128_t)0x2360ed051fc65da4ULL) << 64) | 0x4385df649fccf645ULL;
  g.state = g.state * MULT + g.inc;
}

static inline uint64_t pcg_output(const PCG64 &g) {
  uint64_t hi = (uint64_t)(g.state >> 64);
  uint64_t lo = (uint64_t)g.state;
  uint64_t x = hi ^ lo;
  unsigned rot = (unsigned)(g.state >> 122) & 63u;
  return (x >> rot) | (x << ((64u - rot) & 63u));
}

static inline uint64_t pcg_next64(PCG64 &g) { pcg_step(g); return pcg_output(g); }

static inline uint32_t pcg_next32(PCG64 &g) {
  if (g.has_uint32) { g.has_uint32 = false; return g.uinteger; }
  uint64_t n = pcg_next64(g);
  g.has_uint32 = true;
  g.uinteger = (uint32_t)(n >> 32);
  return (uint32_t)(n & 0xffffffffu);
}

static inline void pcg_seed_from_seedseq0(PCG64 &g) {
  const uint32_t MULT_A = 0x931e8875u;
  const uint32_t MULT_B = 0x58f38dedu;
  const uint32_t MIX_L  = 0xca01f9ddu;
  const uint32_t MIX_R  = 0x4973f715u;
  uint32_t hc = 0x43b0d7e5u;  // INIT_A
  uint32_t pool[4];
  for (int i = 0; i < 4; i++) {
    uint32_t v = 0u;
    v ^= hc; hc *= MULT_A; v *= hc; v ^= v >> 16;
    pool[i] = v;
  }
  for (int is = 0; is < 4; is++) {
    for (int id = 0; id < 4; id++) {
      if (is == id) continue;
      uint32_t h = pool[is];
      h ^= hc; hc *= MULT_A; h *= hc; h ^= h >> 16;
      uint32_t r = (pool[id] * MIX_L) ^ (h * MIX_R);
      r ^= r >> 16;
      pool[id] = r;
    }
  }
  uint32_t hb = 0x8b51f9ddu;  // INIT_B
  uint32_t w[8];
  for (int i = 0; i < 8; i++) {
    uint32_t v = pool[i & 3];
    v ^= hb; hb *= MULT_B; v *= hb; v ^= v >> 16;
    w[i] = v;
  }
  uint64_t sv[4];
  for (int k = 0; k < 4; k++)
    sv[k] = (uint64_t)w[2 * k] | ((uint64_t)w[2 * k + 1] << 32);
  __uint128_t initstate = (((__uint128_t)sv[0]) << 64) | sv[1];
  __uint128_t initseq   = (((__uint128_t)sv[2]) << 64) | sv[3];
  g.state = 0; g.inc = (initseq << 1) | 1;
  pcg_step(g);
  g.state += initstate;
  pcg_step(g);
  g.has_uint32 = false; g.uinteger = 0;
}

static inline uint32_t bounded32(PCG64 &g, uint32_t rng /*inclusive max*/) {
  if (rng == 0) return 0;
  const uint32_t rng_excl = rng + 1u;
  uint64_t m = (uint64_t)pcg_next32(g) * (uint64_t)rng_excl;
  uint32_t leftover = (uint32_t)m;
  if (leftover < rng_excl) {
    const uint32_t threshold = (uint32_t)(0xffffffffu - rng) % rng_excl;
    while (leftover < threshold) {
      m = (uint64_t)pcg_next32(g) * (uint64_t)rng_excl;
      leftover = (uint32_t)m;
    }
  }
  return (uint32_t)(m >> 32);
}

static inline void choice3_2048(PCG64 &g, long long idx[3]) {
  const int pop = 2048, sz = 3;
  uint64_t hs[4] = { (uint64_t)-1, (uint64_t)-1, (uint64_t)-1, (uint64_t)-1 };
  const uint64_t mask = 3;
  for (int j = pop - sz; j < pop; j++) {
    uint64_t val = (uint64_t)bounded32(g, (uint32_t)j);
    uint64_t loc = val & mask;
    while (hs[loc] != (uint64_t)-1 && hs[loc] != val) loc = (loc + 1) & mask;
    if (hs[loc] == (uint64_t)-1) {
      hs[loc] = val;
      idx[j - pop + sz] = (long long)val;
    } else {
      loc = (uint64_t)j & mask;
      while (hs[loc] != (uint64_t)-1) loc = (loc + 1) & mask;
      hs[loc] = (uint64_t)j;
      idx[j - pop + sz] = (long long)j;
    }
  }
  for (int i = 2; i >= 1; i--) {
    uint32_t j = bounded32(g, (uint32_t)i);
    long long t = idx[j]; idx[j] = idx[i]; idx[i] = t;
  }
}

}  // namespace nprng

// ==================== kernel 0: W -> fragment-major bf16 WTc ==================
// WTc layout (short8 units): u = ((((p*8+kc)*2 + nch)*4 + ks)*2 + f)*64 + l
// unit content, element j: W[(kc*128 + ks*32 + (l>>4)*8 + j)*64 + nch*32 + f*16 + (l&15)]
// i.e. exactly the MFMA B-fragment wave (col-half nch) lane l needs for (kc,ks,f).
__global__ __launch_bounds__(256) void wtrans_kernel(
    const float* __restrict__ Wq, const float* __restrict__ Wk,
    const float* __restrict__ Wv, unsigned short* __restrict__ WTc) {
  const int u = blockIdx.x * 256 + threadIdx.x;   // 0 .. 24575 short8 units
  const int l   = u & 63;
  const int fi  = (u >> 6) & 7;    // fi = ks*2 + f
  const int nch = (u >> 9) & 1;
  const int kc  = (u >> 10) & 7;
  const int p   = u >> 13;         // 0..2
  const int f   = fi & 1;
  const int ks  = fi >> 1;
  const float* W = (p == 0) ? Wq : (p == 1) ? Wk : Wv;
  const int n  = nch * 32 + f * 16 + (l & 15);
  const int k0 = kc * 128 + ks * 32 + ((l >> 4) * 8);
  short8 v;
#pragma unroll
  for (int j = 0; j < 8; j++) v[j] = (short)f2bf(W[(size_t)(k0 + j) * 64 + n]);
  *((short8*)WTc + u) = v;
}

// ======== projections: barrier-free streaming bf16 MFMA GEMM ==================
// grid 1536 x 128 thr (2 waves). Block = 16 rows of the concatenated 24576-row
// [q;k;v] input, full 64 output cols; wave w owns col-half w*32. No LDS in the
// main loop: X is read straight from global (lane (lx,quad) streams row m0+lx,
// quad-pairs share 64-B lines -> full line utilization), W fragments come from
// the fragment-major WTc (L2/L1 resident) into registers. X is double-buffered
// in VGPRs one chunk deep; waves are fully independent until the epilogue.
// 6 blocks/CU (12 waves) in exactly one dispatch round (1536 = 6*256).
__global__ __launch_bounds__(128, 3) void proj_kernel(
    const float* __restrict__ xq, const float* __restrict__ xk,
    const float* __restrict__ xv, const unsigned short* __restrict__ WTc,
    const float* __restrict__ bq, const float* __restrict__ bk,
    const float* __restrict__ bv,
    unsigned short* __restrict__ Qf, unsigned short* __restrict__ Kf,
    unsigned short* __restrict__ Vf) {
  const int bid  = blockIdx.x;
  const int proj = bid >> 9;               // 512 blocks per projection
  const int m0   = (bid & 511) << 4;       // row within proj (16-row block)
  const float* X    = (proj == 0) ? xq : (proj == 1) ? xk : xv;
  const float* bias = (proj == 0) ? bq : (proj == 1) ? bk : bv;

  const int tid  = threadIdx.x;
  const int w    = tid >> 6;               // col-half
  const int l    = tid & 63;
  const int quad = l >> 4;
  const int lx   = l & 15;

  const float* Xr = X + (size_t)(m0 + lx) * DIN + quad * 8;  // lane's row slice
  const short8* W8 = (const short8*)WTc;

  floatx4 acc0 = {0.f, 0.f, 0.f, 0.f}, acc1 = acc0;
  float4 xa[8], xb[8];

  auto LDX = [&](int kc, float4* xr) {
#pragma unroll
    for (int ks = 0; ks < 4; ks++) {
      const float* p = Xr + kc * 128 + ks * 32;
      xr[2 * ks]     = *(const float4*)(p);
      xr[2 * ks + 1] = *(const float4*)(p + 4);
    }
  };
  auto CHUNK = [&](int kc, const float4* xr) {
    const short8* Wk8 = W8 + ((((size_t)proj * 8 + kc) * 2 + w) * 8) * 64 + l;
    short8 wf[8];
#pragma unroll
    for (int i = 0; i < 8; i++) wf[i] = Wk8[i * 64];
#pragma unroll
    for (int ks = 0; ks < 4; ks++) {
      const float4 f0 = xr[2 * ks], f1 = xr[2 * ks + 1];
      short8 a;
      a[0] = f2bf(f0.x); a[1] = f2bf(f0.y); a[2] = f2bf(f0.z); a[3] = f2bf(f0.w);
      a[4] = f2bf(f1.x); a[5] = f2bf(f1.y); a[6] = f2bf(f1.z); a[7] = f2bf(f1.w);
      acc0 = MFMA16(a, wf[ks * 2],     acc0);
      acc1 = MFMA16(a, wf[ks * 2 + 1], acc1);
    }
  };

  LDX(0, xa);
#pragma unroll
  for (int kk = 0; kk < 4; kk++) {
    LDX(2 * kk + 1, xb);              // prefetch odd chunk while even computes
    CHUNK(2 * kk, xa);
    if (kk < 3) LDX(2 * kk + 2, xa);  // prefetch next even chunk
    CHUNK(2 * kk + 1, xb);
  }

  // ---- epilogue: stage 16x64 tile (+bias) in LDS, emit fragment layouts ----
  __shared__ float Cs[16][68];
  const float bb0 = bias[w * 32 + lx], bb1 = bias[w * 32 + 16 + lx];
#pragma unroll
  for (int i = 0; i < 4; i++) {
    Cs[quad * 4 + i][w * 32 + lx]      = acc0[i] + bb0;
    Cs[quad * 4 + i][w * 32 + 16 + lx] = acc1[i] + bb1;
  }
  __syncthreads();

  const int b_  = m0 >> 11;                // batch
  const int s0  = m0 & 2047;               // seq offset within batch
  const int ll  = tid & 63, lxx = ll & 15, qq = ll >> 4;

  if (proj == 0) {
    // Qf: per (b, qt) 2048 B: frag s(2) x lane(64) x 16 B
    const int s = tid >> 6;
    short8 v;
#pragma unroll
    for (int j = 0; j < 8; j++) v[j] = (short)f2bf(Cs[lxx][s * 32 + qq * 8 + j]);
    char* dst = (char*)Qf + ((size_t)(b_ * 128 + (s0 >> 4))) * 2048 + s * 1024 + ll * 16;
    *(short8*)dst = v;
  } else if (proj == 1) {
    // Kf: per (b, t=64-row tile) 8192 B: frag (c*2+s); this block owns one c.
    const int s = tid >> 6;
    const int c = (s0 >> 4) & 3;
    short8 v;
#pragma unroll
    for (int j = 0; j < 8; j++) v[j] = (short)f2bf(Cs[lxx][s * 32 + qq * 8 + j]);
    char* dst = (char*)Kf + ((size_t)(b_ * 32 + (s0 >> 6))) * 8192 + (c * 2 + s) * 1024 + ll * 16;
    *(short8*)dst = v;
  } else {
    // Vf: frag (sf*4+c), lane lv -> V[t*64+sf*32+(lv>>4)*8+j][16c+(lv&15)].
    // A frag spans 32 seq rows; this 16-row block fills lane half h of 4 frags.
    const int h  = (s0 >> 4) & 1;          // which 16-row half of the 32-row span
    const int sf = (s0 >> 5) & 1;
    const int c  = tid >> 5;               // 0..3
    const int lv = h * 32 + (tid & 31);    // destination lane within frag
    const int q2 = (lv >> 4) & 1;          // row-octet within this block
    const int lxv = lv & 15;
    short8 v;
#pragma unroll
    for (int j = 0; j < 8; j++) v[j] = (short)f2bf(Cs[q2 * 8 + j][c * 16 + lxv]);
    char* dst = (char*)Vf + ((size_t)(b_ * 32 + (s0 >> 6))) * 8192 + (sf * 4 + c) * 1024 + lv * 16;
    *(short8*)dst = v;
  }
}

// ============ flash attention: fragment-major direct loads, 1 barrier =========
// grid (128, 4), 256 threads (4 waves). Block = 16 q-rows; wave w processes
// key-tiles t = w, w+4, ... with independent online-softmax state; merged once.
// All Q/K/V fragment loads are per-wave LINEAR global reads (chunk + lane*16):
// perfect coalescing, no LDS staging, no barriers, no bank conflicts.
__global__ __launch_bounds__(256, 2) void attn_kernel(
    const unsigned short* __restrict__ Qf, const unsigned short* __restrict__ Kf,
    const unsigned short* __restrict__ Vf, float* __restrict__ out,
    int R0, int C0, int R1, int C1, int R2, int C2) {
  const int b    = blockIdx.y;
  const int bx   = blockIdx.x;
  const int qi   = (bx & 1) ? (127 - (bx >> 1)) : (bx >> 1);  // heavy/light pairing
  const int q0   = qi * 16;
  const int tid  = threadIdx.x;
  const int w    = tid >> 6;
  const int l    = tid & 63;
  const int quad = l >> 4;
  const int lx   = l & 15;

  __shared__ unsigned short Ps[4][16][72];
  __shared__ float Os[4][16][64];
  __shared__ float mS[4][16], lS[4][16];
  __shared__ float lgS[3];
  __shared__ int   lgF[3];

  const char* Qc = (const char*)Qf + ((size_t)(b * 128 + qi)) * 2048 + l * 16;
  const short8 aq0 = *(const short8*)Qc;
  const short8 aq1 = *(const short8*)(Qc + 1024);

  floatx4 O[4];
  float m_i[4], l_i[4];
#pragma unroll
  for (int c = 0; c < 4; c++) O[c] = (floatx4){0.f, 0.f, 0.f, 0.f};
#pragma unroll
  for (int i = 0; i < 4; i++) { m_i[i] = -INFINITY; l_i[i] = 0.f; }

  const int T = (q0 + 79) >> 6;   // key-tiles needed (64 keys each)

  for (int t = w; t < T; t += 4) {
    const int k0 = t << 6;
    const bool mT = (t == T - 1);

    const char* Kc = (const char*)Kf + ((size_t)(b * 32 + t)) * 8192 + l * 16;
    const char* Vc = (const char*)Vf + ((size_t)(b * 32 + t)) * 8192 + l * 16;
    short8 kf[8], vf[8];
#pragma unroll
    for (int f = 0; f < 8; f++) {
      kf[f] = *(const short8*)(Kc + f * 1024);
      vf[f] = *(const short8*)(Vc + f * 1024);
    }

    floatx4 sc[4];
    __builtin_amdgcn_s_setprio(1);
#pragma unroll
    for (int c = 0; c < 4; c++) {
      sc[c] = (floatx4){0.f, 0.f, 0.f, 0.f};
      sc[c] = MFMA16(aq0, kf[2 * c], sc[c]);
      sc[c] = MFMA16(aq1, kf[2 * c + 1], sc[c]);
    }
    __builtin_amdgcn_s_setprio(0);

    float mt[4], al[4];
#pragma unroll
    for (int i = 0; i < 4; i++) {
      const int rowg = q0 + quad * 4 + i;
      float vmax = -INFINITY;
#pragma unroll
      for (int c = 0; c < 4; c++) {
        float v = sc[c][i] * 0.125f;
        if (mT && (k0 + 16 * c + lx) > rowg) v = -INFINITY;
        sc[c][i] = v;
        vmax = fmaxf(vmax, v);
      }
      mt[i] = vmax;
    }
#pragma unroll
    for (int i = 0; i < 4; i++) {
#pragma unroll
      for (int off = 8; off >= 1; off >>= 1)
        mt[i] = fmaxf(mt[i], __shfl_xor(mt[i], off));
      const float mn = fmaxf(m_i[i], mt[i]);
      al[i] = __expf(m_i[i] - mn);
      m_i[i] = mn;
      float s = 0.f;
#pragma unroll
      for (int c = 0; c < 4; c++) {
        float p = __expf(sc[c][i] - mn);
        Ps[w][quad * 4 + i][16 * c + lx] = f2bf(p);
        s += p;
      }
#pragma unroll
      for (int off = 8; off >= 1; off >>= 1) s += __shfl_xor(s, off);
      l_i[i] = l_i[i] * al[i] + s;
    }
#pragma unroll
    for (int c = 0; c < 4; c++)
#pragma unroll
      for (int i = 0; i < 4; i++) O[c][i] *= al[i];
    asm volatile("" ::: "memory");  // keep ds_reads below the ds_writes above
    const short8 pf0 = *(const short8*)&Ps[w][lx][quad * 8];
    const short8 pf1 = *(const short8*)&Ps[w][lx][32 + quad * 8];
    __builtin_amdgcn_s_setprio(1);
#pragma unroll
    for (int c = 0; c < 4; c++) {
      O[c] = MFMA16(pf0, vf[c],     O[c]);
      O[c] = MFMA16(pf1, vf[4 + c], O[c]);
    }
    __builtin_amdgcn_s_setprio(0);
  }

  // deposit per-wave state
  if (lx == 0) {
#pragma unroll
    for (int i = 0; i < 4; i++) {
      mS[w][quad * 4 + i] = m_i[i];
      lS[w][quad * 4 + i] = l_i[i];
    }
  }
#pragma unroll
  for (int c = 0; c < 4; c++)
#pragma unroll
    for (int i = 0; i < 4; i++) Os[w][quad * 4 + i][16 * c + lx] = O[c][i];

  // wave 0: logits for global pairs above the diagonal (lane l owns dim d=l)
  if (w == 0) {
#pragma unroll
    for (int p = 0; p < 3; p++) {
      const int R = (p == 0) ? R0 : (p == 1) ? R1 : R2;
      const int C = (p == 0) ? C0 : (p == 1) ? C1 : C2;
      const int act = (R >= q0 && R < q0 + 16 && C > R);
      float d = 0.f;
      if (act) {
        const int dd = l;
        const char* qa = (const char*)Qf + ((size_t)(b * 128 + (R >> 4))) * 2048 +
                         (dd >> 5) * 1024 + ((R & 15) + ((dd >> 3) & 3) * 16) * 16 + (dd & 7) * 2;
        const char* ka = (const char*)Kf + ((size_t)(b * 32 + (C >> 6))) * 8192 +
                         (((C >> 4) & 3) * 2 + (dd >> 5)) * 1024 +
                         ((C & 15) + ((dd >> 3) & 3) * 16) * 16 + (dd & 7) * 2;
        d = bf2f(*(const unsigned short*)qa) * bf2f(*(const unsigned short*)ka);
#pragma unroll
        for (int off = 32; off >= 1; off >>= 1) d += __shfl_xor(d, off);
        d *= 0.125f;
      }
      if (l == 0) { lgF[p] = act; lgS[p] = d; }
    }
  }
  __syncthreads();

  // merge the 4 wave states (+ pair fixups), normalize, store
  {
    const int row = tid >> 4;          // 0..15
    const int d0  = (tid & 15) * 4;    // 0..60
    const int Rs[3] = {R0, R1, R2};
    const int Cs3[3] = {C0, C1, C2};

    float mf = -INFINITY;
#pragma unroll
    for (int w4 = 0; w4 < 4; w4++) mf = fmaxf(mf, mS[w4][row]);
#pragma unroll
    for (int p = 0; p < 3; p++)
      if (lgF[p] && (Rs[p] - q0) == row) mf = fmaxf(mf, lgS[p]);

    float lf = 0.f;
    float o0 = 0.f, o1 = 0.f, o2 = 0.f, o3 = 0.f;
#pragma unroll
    for (int w4 = 0; w4 < 4; w4++) {
      const float a = __expf(mS[w4][row] - mf);
      lf += a * lS[w4][row];
      const float* op = &Os[w4][row][d0];
      o0 += a * op[0]; o1 += a * op[1]; o2 += a * op[2]; o3 += a * op[3];
    }
#pragma unroll
    for (int p = 0; p < 3; p++) {
      if (lgF[p] && (Rs[p] - q0) == row) {
        const float pe = __expf(lgS[p] - mf);
        lf += pe;
        const int C = Cs3[p];
        float vv[4];
#pragma unroll
        for (int j = 0; j < 4; j++) {
          const int dim = d0 + j;
          const char* va = (const char*)Vf + ((size_t)(b * 32 + (C >> 6))) * 8192 +
                           (((C >> 5) & 1) * 4 + (dim >> 4)) * 1024 +
                           ((dim & 15) + ((C >> 3) & 3) * 16) * 16 + (C & 7) * 2;
          vv[j] = bf2f(*(const unsigned short*)va);
        }
        o0 += pe * vv[0]; o1 += pe * vv[1]; o2 += pe * vv[2]; o3 += pe * vv[3];
      }
    }
    const float inv = 1.0f / lf;
    float4 r;
    r.x = o0 * inv; r.y = o1 * inv; r.z = o2 * inv; r.w = o3 * inv;
    *(float4*)(out + ((size_t)b * SEQ + q0 + row) * 64 + d0) = r;
  }
}

// ================================= launch =====================================
extern "C" void kernel_launch(void* const* d_in, const int* in_sizes, int n_in,
                              void* d_out, int out_size, void* d_ws,
                              size_t ws_size, hipStream_t stream) {
  const float* xq = (const float*)d_in[0];
  const float* xk = (const float*)d_in[1];
  const float* xv = (const float*)d_in[2];
  const float* Wq = (const float*)d_in[3];
  const float* bq = (const float*)d_in[4];
  const float* Wk = (const float*)d_in[5];
  const float* bk = (const float*)d_in[6];
  const float* Wv = (const float*)d_in[7];
  const float* bv = (const float*)d_in[8];
  float* out = (float*)d_out;

  // workspace (bf16): Qf 1MB, Kf 1MB, Vf 1MB, WTc 384KB (fragment-major layouts)
  unsigned short* Qf  = (unsigned short*)d_ws;
  unsigned short* Kf  = Qf + (size_t)NBATCH * SEQ * 64;
  unsigned short* Vf  = Kf + (size_t)NBATCH * SEQ * 64;
  unsigned short* WTc = Vf + (size_t)NBATCH * SEQ * 64;

  nprng::PCG64 g;
  nprng::pcg_seed_from_seedseq0(g);
  long long rows[3], cols[3];
  nprng::choice3_2048(g, rows);
  nprng::choice3_2048(g, cols);

  wtrans_kernel<<<96, 256, 0, stream>>>(Wq, Wk, Wv, WTc);

  proj_kernel<<<1536, 128, 0, stream>>>(xq, xk, xv, WTc, bq, bk, bv, Qf, Kf, Vf);

  dim3 agrid(SEQ / 16, NBATCH);
  attn_kernel<<<agrid, 256, 0, stream>>>(
      Qf, Kf, Vf, out, (int)rows[0], (int)cols[0], (int)rows[1], (int)cols[1],
      (int)rows[2], (int)cols[2]);
}

// Round 2
// 168.182 us; speedup vs baseline: 1.0003x; 1.0003x over previous
//
#include <hip/hip_runtime.h>
#include <cstdint>
#include <cstddef>
#include <math.h>

#define SEQ    2048
#define NBATCH 4
#define DIN    1024
#define DH     64

typedef __attribute__((ext_vector_type(8))) short  short8;   // 8 x bf16 (4 VGPRs)
typedef __attribute__((ext_vector_type(4))) float  floatx4;  // MFMA C/D

#define MFMA16(a, b, c) __builtin_amdgcn_mfma_f32_16x16x32_bf16((a), (b), (c), 0, 0, 0)

__device__ __forceinline__ unsigned short f2bf(float x) {
  unsigned u = __float_as_uint(x);
  return (unsigned short)((u + 0x8000u) >> 16);   // round-half-up; values finite
}
__device__ __forceinline__ float bf2f(unsigned short h) {
  return __uint_as_float(((unsigned)h) << 16);
}

// ======================= host-side numpy RNG replication =======================
namespace nprng {

struct PCG64 {
  __uint128_t state, inc;
  bool has_uint32;
  uint32_t uinteger;
};

static inline void pcg_step(PCG64 &g) {
  const __uint128_t MULT =
      (((__uint128_t)0x2360ed051fc65da4ULL) << 64) | 0x4385df649fccf645ULL;
  g.state = g.state * MULT + g.inc;
}

static inline uint64_t pcg_output(const PCG64 &g) {
  uint64_t hi = (uint64_t)(g.state >> 64);
  uint64_t lo = (uint64_t)g.state;
  uint64_t x = hi ^ lo;
  unsigned rot = (unsigned)(g.state >> 122) & 63u;
  return (x >> rot) | (x << ((64u - rot) & 63u));
}

static inline uint64_t pcg_next64(PCG64 &g) { pcg_step(g); return pcg_output(g); }

static inline uint32_t pcg_next32(PCG64 &g) {
  if (g.has_uint32) { g.has_uint32 = false; return g.uinteger; }
  uint64_t n = pcg_next64(g);
  g.has_uint32 = true;
  g.uinteger = (uint32_t)(n >> 32);
  return (uint32_t)(n & 0xffffffffu);
}

static inline void pcg_seed_from_seedseq0(PCG64 &g) {
  const uint32_t MULT_A = 0x931e8875u;
  const uint32_t MULT_B = 0x58f38dedu;
  const uint32_t MIX_L  = 0xca01f9ddu;
  const uint32_t MIX_R  = 0x4973f715u;
  uint32_t hc = 0x43b0d7e5u;  // INIT_A
  uint32_t pool[4];
  for (int i = 0; i < 4; i++) {
    uint32_t v = 0u;
    v ^= hc; hc *= MULT_A; v *= hc; v ^= v >> 16;
    pool[i] = v;
  }
  for (int is = 0; is < 4; is++) {
    for (int id = 0; id < 4; id++) {
      if (is == id) continue;
      uint32_t h = pool[is];
      h ^= hc; hc *= MULT_A; h *= hc; h ^= h >> 16;
      uint32_t r = (pool[id] * MIX_L) ^ (h * MIX_R);
      r ^= r >> 16;
      pool[id] = r;
    }
  }
  uint32_t hb = 0x8b51f9ddu;  // INIT_B
  uint32_t w[8];
  for (int i = 0; i < 8; i++) {
    uint32_t v = pool[i & 3];
    v ^= hb; hb *= MULT_B; v *= hb; v ^= v >> 16;
    w[i] = v;
  }
  uint64_t sv[4];
  for (int k = 0; k < 4; k++)
    sv[k] = (uint64_t)w[2 * k] | ((uint64_t)w[2 * k + 1] << 32);
  __uint128_t initstate = (((__uint128_t)sv[0]) << 64) | sv[1];
  __uint128_t initseq   = (((__uint128_t)sv[2]) << 64) | sv[3];
  g.state = 0; g.inc = (initseq << 1) | 1;
  pcg_step(g);
  g.state += initstate;
  pcg_step(g);
  g.has_uint32 = false; g.uinteger = 0;
}

static inline uint32_t bounded32(PCG64 &g, uint32_t rng /*inclusive max*/) {
  if (rng == 0) return 0;
  const uint32_t rng_excl = rng + 1u;
  uint64_t m = (uint64_t)pcg_next32(g) * (uint64_t)rng_excl;
  uint32_t leftover = (uint32_t)m;
  if (leftover < rng_excl) {
    const uint32_t threshold = (uint32_t)(0xffffffffu - rng) % rng_excl;
    while (leftover < threshold) {
      m = (uint64_t)pcg_next32(g) * (uint64_t)rng_excl;
      leftover = (uint32_t)m;
    }
  }
  return (uint32_t)(m >> 32);
}

static inline void choice3_2048(PCG64 &g, long long idx[3]) {
  const int pop = 2048, sz = 3;
  uint64_t hs[4] = { (uint64_t)-1, (uint64_t)-1, (uint64_t)-1, (uint64_t)-1 };
  const uint64_t mask = 3;
  for (int j = pop - sz; j < pop; j++) {
    uint64_t val = (uint64_t)bounded32(g, (uint32_t)j);
    uint64_t loc = val & mask;
    while (hs[loc] != (uint64_t)-1 && hs[loc] != val) loc = (loc + 1) & mask;
    if (hs[loc] == (uint64_t)-1) {
      hs[loc] = val;
      idx[j - pop + sz] = (long long)val;
    } else {
      loc = (uint64_t)j & mask;
      while (hs[loc] != (uint64_t)-1) loc = (loc + 1) & mask;
      hs[loc] = (uint64_t)j;
      idx[j - pop + sz] = (long long)j;
    }
  }
  for (int i = 2; i >= 1; i--) {
    uint32_t j = bounded32(g, (uint32_t)i);
    long long t = idx[j]; idx[j] = idx[i]; idx[i] = t;
  }
}

}  // namespace nprng

// ==================== kernel 0: W -> fragment-major bf16 WTc ==================
// WTc layout (short8 units): u = ((((p*8+kc)*2 + nch)*4 + ks)*2 + f)*64 + l
// unit content, element j: W[(kc*128 + ks*32 + (l>>4)*8 + j)*64 + nch*32 + f*16 + (l&15)]
// i.e. exactly the MFMA B-fragment wave (col-half nch) lane l needs for (kc,ks,f).
__global__ __launch_bounds__(256) void wtrans_kernel(
    const float* __restrict__ Wq, const float* __restrict__ Wk,
    const float* __restrict__ Wv, unsigned short* __restrict__ WTc) {
  const int u = blockIdx.x * 256 + threadIdx.x;   // 0 .. 24575 short8 units
  const int l   = u & 63;
  const int fi  = (u >> 6) & 7;    // fi = ks*2 + f
  const int nch = (u >> 9) & 1;
  const int kc  = (u >> 10) & 7;
  const int p   = u >> 13;         // 0..2
  const int f   = fi & 1;
  const int ks  = fi >> 1;
  const float* W = (p == 0) ? Wq : (p == 1) ? Wk : Wv;
  const int n  = nch * 32 + f * 16 + (l & 15);
  const int k0 = kc * 128 + ks * 32 + ((l >> 4) * 8);
  short8 v;
#pragma unroll
  for (int j = 0; j < 8; j++) v[j] = (short)f2bf(W[(size_t)(k0 + j) * 64 + n]);
  *((short8*)WTc + u) = v;
}

// ======== projections: barrier-free streaming bf16 MFMA GEMM ==================
// grid 1536 x 128 thr (2 waves). Block = 16 rows of the concatenated 24576-row
// [q;k;v] input, full 64 output cols; wave w owns col-half w*32. No LDS in the
// main loop: X is read straight from global (lane (lx,quad) streams row m0+lx),
// W fragments from the fragment-major WTc (L2-resident) into registers. Both
// are double-buffered in VGPRs one 128-K chunk deep; sched_barrier(0) after
// each load group pins the pipeline (round-1 lesson: without the fence the
// compiler sinks loads to their use, VGPR_Count collapsed to 32 and the loop
// became latency-serialized at 47 us). 6 blocks/CU = 12 waves/CU, one round.
__global__ __launch_bounds__(128, 3) void proj_kernel(
    const float* __restrict__ xq, const float* __restrict__ xk,
    const float* __restrict__ xv, const unsigned short* __restrict__ WTc,
    const float* __restrict__ bq, const float* __restrict__ bk,
    const float* __restrict__ bv,
    unsigned short* __restrict__ Qf, unsigned short* __restrict__ Kf,
    unsigned short* __restrict__ Vf) {
  const int bid  = blockIdx.x;
  const int proj = bid >> 9;               // 512 blocks per projection
  const int m0   = (bid & 511) << 4;       // row within proj (16-row block)
  const float* X    = (proj == 0) ? xq : (proj == 1) ? xk : xv;
  const float* bias = (proj == 0) ? bq : (proj == 1) ? bk : bv;

  const int tid  = threadIdx.x;
  const int w    = tid >> 6;               // col-half
  const int l    = tid & 63;
  const int quad = l >> 4;
  const int lx   = l & 15;

  const float* Xr = X + (size_t)(m0 + lx) * DIN + quad * 8;  // lane's row slice
  const short8* Wbase =
      (const short8*)WTc + (((size_t)proj * 8 * 2 + w) * 8) * 64 + l;
  // chunk-to-chunk stride in short8 units: 2*8*64 = 1024

  floatx4 acc0 = {0.f, 0.f, 0.f, 0.f}, acc1 = acc0;
  float4 xa[8], xb[8];
  short8 wa[8], wb[8];

  auto LDX = [&](int kc, float4* xr) {
#pragma unroll
    for (int ks = 0; ks < 4; ks++) {
      const float* p = Xr + kc * 128 + ks * 32;
      xr[2 * ks]     = *(const float4*)(p);
      xr[2 * ks + 1] = *(const float4*)(p + 4);
    }
  };
  auto LDW = [&](int kc, short8* wr) {
    const short8* Wk8 = Wbase + (size_t)kc * 1024;
#pragma unroll
    for (int i = 0; i < 8; i++) wr[i] = Wk8[i * 64];
  };
  auto CHUNK = [&](const float4* xr, const short8* wr) {
#pragma unroll
    for (int ks = 0; ks < 4; ks++) {
      const float4 f0 = xr[2 * ks], f1 = xr[2 * ks + 1];
      short8 a;
      a[0] = f2bf(f0.x); a[1] = f2bf(f0.y); a[2] = f2bf(f0.z); a[3] = f2bf(f0.w);
      a[4] = f2bf(f1.x); a[5] = f2bf(f1.y); a[6] = f2bf(f1.z); a[7] = f2bf(f1.w);
      acc0 = MFMA16(a, wr[2 * ks],     acc0);
      acc1 = MFMA16(a, wr[2 * ks + 1], acc1);
    }
  };

  // prologue: chunks 0 and 1 in flight
  LDX(0, xa); LDW(0, wa);
  LDX(1, xb); LDW(1, wb);
  __builtin_amdgcn_sched_barrier(0);
#pragma unroll
  for (int kk = 0; kk < 4; kk++) {
    CHUNK(xa, wa);                                     // compute chunk 2kk
    if (kk < 3) { LDX(2 * kk + 2, xa); LDW(2 * kk + 2, wa); }
    __builtin_amdgcn_sched_barrier(0);                 // pin: loads stay above
    CHUNK(xb, wb);                                     // compute chunk 2kk+1
    if (kk < 3) { LDX(2 * kk + 3, xb); LDW(2 * kk + 3, wb); }
    __builtin_amdgcn_sched_barrier(0);
  }

  // ---- epilogue: stage 16x64 tile (+bias) in LDS, emit fragment layouts ----
  __shared__ float Cs[16][68];
  const float bb0 = bias[w * 32 + lx], bb1 = bias[w * 32 + 16 + lx];
#pragma unroll
  for (int i = 0; i < 4; i++) {
    Cs[quad * 4 + i][w * 32 + lx]      = acc0[i] + bb0;
    Cs[quad * 4 + i][w * 32 + 16 + lx] = acc1[i] + bb1;
  }
  __syncthreads();

  const int b_  = m0 >> 11;                // batch
  const int s0  = m0 & 2047;               // seq offset within batch
  const int ll  = tid & 63, lxx = ll & 15, qq = ll >> 4;

  if (proj == 0) {
    // Qf: per (b, qt) 2048 B: frag s(2) x lane(64) x 16 B
    const int s = tid >> 6;
    short8 v;
#pragma unroll
    for (int j = 0; j < 8; j++) v[j] = (short)f2bf(Cs[lxx][s * 32 + qq * 8 + j]);
    char* dst = (char*)Qf + ((size_t)(b_ * 128 + (s0 >> 4))) * 2048 + s * 1024 + ll * 16;
    *(short8*)dst = v;
  } else if (proj == 1) {
    // Kf: per (b, t=64-row tile) 8192 B: frag (c*2+s); this block owns one c.
    const int s = tid >> 6;
    const int c = (s0 >> 4) & 3;
    short8 v;
#pragma unroll
    for (int j = 0; j < 8; j++) v[j] = (short)f2bf(Cs[lxx][s * 32 + qq * 8 + j]);
    char* dst = (char*)Kf + ((size_t)(b_ * 32 + (s0 >> 6))) * 8192 + (c * 2 + s) * 1024 + ll * 16;
    *(short8*)dst = v;
  } else {
    // Vf: frag (sf*4+c), lane lv -> V[t*64+sf*32+(lv>>4)*8+j][16c+(lv&15)].
    // A frag spans 32 seq rows; this 16-row block fills lane half h of 4 frags.
    const int h  = (s0 >> 4) & 1;          // which 16-row half of the 32-row span
    const int sf = (s0 >> 5) & 1;
    const int c  = tid >> 5;               // 0..3
    const int lv = h * 32 + (tid & 31);    // destination lane within frag
    const int q2 = (lv >> 4) & 1;          // row-octet within this block
    const int lxv = lv & 15;
    short8 v;
#pragma unroll
    for (int j = 0; j < 8; j++) v[j] = (short)f2bf(Cs[q2 * 8 + j][c * 16 + lxv]);
    char* dst = (char*)Vf + ((size_t)(b_ * 32 + (s0 >> 6))) * 8192 + (sf * 4 + c) * 1024 + lv * 16;
    *(short8*)dst = v;
  }
}

// ============ flash attention: fragment-major direct loads, 1 barrier =========
// grid (128, 4), 256 threads (4 waves). Block = 16 q-rows; wave w processes
// key-tiles t = w, w+4, ... with independent online-softmax state; merged once.
// All Q/K/V fragment loads are per-wave LINEAR global reads (chunk + lane*16):
// perfect coalescing, no LDS staging, no barriers, no bank conflicts.
__global__ __launch_bounds__(256, 2) void attn_kernel(
    const unsigned short* __restrict__ Qf, const unsigned short* __restrict__ Kf,
    const unsigned short* __restrict__ Vf, float* __restrict__ out,
    int R0, int C0, int R1, int C1, int R2, int C2) {
  const int b    = blockIdx.y;
  const int bx   = blockIdx.x;
  const int qi   = (bx & 1) ? (127 - (bx >> 1)) : (bx >> 1);  // heavy/light pairing
  const int q0   = qi * 16;
  const int tid  = threadIdx.x;
  const int w    = tid >> 6;
  const int l    = tid & 63;
  const int quad = l >> 4;
  const int lx   = l & 15;

  __shared__ unsigned short Ps[4][16][72];
  __shared__ float Os[4][16][64];
  __shared__ float mS[4][16], lS[4][16];
  __shared__ float lgS[3];
  __shared__ int   lgF[3];

  const char* Qc = (const char*)Qf + ((size_t)(b * 128 + qi)) * 2048 + l * 16;
  const short8 aq0 = *(const short8*)Qc;
  const short8 aq1 = *(const short8*)(Qc + 1024);

  floatx4 O[4];
  float m_i[4], l_i[4];
#pragma unroll
  for (int c = 0; c < 4; c++) O[c] = (floatx4){0.f, 0.f, 0.f, 0.f};
#pragma unroll
  for (int i = 0; i < 4; i++) { m_i[i] = -INFINITY; l_i[i] = 0.f; }

  const int T = (q0 + 79) >> 6;   // key-tiles needed (64 keys each)

  for (int t = w; t < T; t += 4) {
    const int k0 = t << 6;
    const bool mT = (t == T - 1);

    const char* Kc = (const char*)Kf + ((size_t)(b * 32 + t)) * 8192 + l * 16;
    const char* Vc = (const char*)Vf + ((size_t)(b * 32 + t)) * 8192 + l * 16;
    short8 kf[8], vf[8];
#pragma unroll
    for (int f = 0; f < 8; f++) {
      kf[f] = *(const short8*)(Kc + f * 1024);
      vf[f] = *(const short8*)(Vc + f * 1024);
    }

    floatx4 sc[4];
    __builtin_amdgcn_s_setprio(1);
#pragma unroll
    for (int c = 0; c < 4; c++) {
      sc[c] = (floatx4){0.f, 0.f, 0.f, 0.f};
      sc[c] = MFMA16(aq0, kf[2 * c], sc[c]);
      sc[c] = MFMA16(aq1, kf[2 * c + 1], sc[c]);
    }
    __builtin_amdgcn_s_setprio(0);

    float mt[4], al[4];
#pragma unroll
    for (int i = 0; i < 4; i++) {
      const int rowg = q0 + quad * 4 + i;
      float vmax = -INFINITY;
#pragma unroll
      for (int c = 0; c < 4; c++) {
        float v = sc[c][i] * 0.125f;
        if (mT && (k0 + 16 * c + lx) > rowg) v = -INFINITY;
        sc[c][i] = v;
        vmax = fmaxf(vmax, v);
      }
      mt[i] = vmax;
    }
#pragma unroll
    for (int i = 0; i < 4; i++) {
#pragma unroll
      for (int off = 8; off >= 1; off >>= 1)
        mt[i] = fmaxf(mt[i], __shfl_xor(mt[i], off));
      const float mn = fmaxf(m_i[i], mt[i]);
      al[i] = __expf(m_i[i] - mn);
      m_i[i] = mn;
      float s = 0.f;
#pragma unroll
      for (int c = 0; c < 4; c++) {
        float p = __expf(sc[c][i] - mn);
        Ps[w][quad * 4 + i][16 * c + lx] = f2bf(p);
        s += p;
      }
#pragma unroll
      for (int off = 8; off >= 1; off >>= 1) s += __shfl_xor(s, off);
      l_i[i] = l_i[i] * al[i] + s;
    }
#pragma unroll
    for (int c = 0; c < 4; c++)
#pragma unroll
      for (int i = 0; i < 4; i++) O[c][i] *= al[i];
    asm volatile("" ::: "memory");  // keep ds_reads below the ds_writes above
    const short8 pf0 = *(const short8*)&Ps[w][lx][quad * 8];
    const short8 pf1 = *(const short8*)&Ps[w][lx][32 + quad * 8];
    __builtin_amdgcn_s_setprio(1);
#pragma unroll
    for (int c = 0; c < 4; c++) {
      O[c] = MFMA16(pf0, vf[c],     O[c]);
      O[c] = MFMA16(pf1, vf[4 + c], O[c]);
    }
    __builtin_amdgcn_s_setprio(0);
  }

  // deposit per-wave state
  if (lx == 0) {
#pragma unroll
    for (int i = 0; i < 4; i++) {
      mS[w][quad * 4 + i] = m_i[i];
      lS[w][quad * 4 + i] = l_i[i];
    }
  }
#pragma unroll
  for (int c = 0; c < 4; c++)
#pragma unroll
    for (int i = 0; i < 4; i++) Os[w][quad * 4 + i][16 * c + lx] = O[c][i];

  // wave 0: logits for global pairs above the diagonal (lane l owns dim d=l)
  if (w == 0) {
#pragma unroll
    for (int p = 0; p < 3; p++) {
      const int R = (p == 0) ? R0 : (p == 1) ? R1 : R2;
      const int C = (p == 0) ? C0 : (p == 1) ? C1 : C2;
      const int act = (R >= q0 && R < q0 + 16 && C > R);
      float d = 0.f;
      if (act) {
        const int dd = l;
        const char* qa = (const char*)Qf + ((size_t)(b * 128 + (R >> 4))) * 2048 +
                         (dd >> 5) * 1024 + ((R & 15) + ((dd >> 3) & 3) * 16) * 16 + (dd & 7) * 2;
        const char* ka = (const char*)Kf + ((size_t)(b * 32 + (C >> 6))) * 8192 +
                         (((C >> 4) & 3) * 2 + (dd >> 5)) * 1024 +
                         ((C & 15) + ((dd >> 3) & 3) * 16) * 16 + (dd & 7) * 2;
        d = bf2f(*(const unsigned short*)qa) * bf2f(*(const unsigned short*)ka);
#pragma unroll
        for (int off = 32; off >= 1; off >>= 1) d += __shfl_xor(d, off);
        d *= 0.125f;
      }
      if (l == 0) { lgF[p] = act; lgS[p] = d; }
    }
  }
  __syncthreads();

  // merge the 4 wave states (+ pair fixups), normalize, store
  {
    const int row = tid >> 4;          // 0..15
    const int d0  = (tid & 15) * 4;    // 0..60
    const int Rs[3] = {R0, R1, R2};
    const int Cs3[3] = {C0, C1, C2};

    float mf = -INFINITY;
#pragma unroll
    for (int w4 = 0; w4 < 4; w4++) mf = fmaxf(mf, mS[w4][row]);
#pragma unroll
    for (int p = 0; p < 3; p++)
      if (lgF[p] && (Rs[p] - q0) == row) mf = fmaxf(mf, lgS[p]);

    float lf = 0.f;
    float o0 = 0.f, o1 = 0.f, o2 = 0.f, o3 = 0.f;
#pragma unroll
    for (int w4 = 0; w4 < 4; w4++) {
      const float a = __expf(mS[w4][row] - mf);
      lf += a * lS[w4][row];
      const float* op = &Os[w4][row][d0];
      o0 += a * op[0]; o1 += a * op[1]; o2 += a * op[2]; o3 += a * op[3];
    }
#pragma unroll
    for (int p = 0; p < 3; p++) {
      if (lgF[p] && (Rs[p] - q0) == row) {
        const float pe = __expf(lgS[p] - mf);
        lf += pe;
        const int C = Cs3[p];
        float vv[4];
#pragma unroll
        for (int j = 0; j < 4; j++) {
          const int dim = d0 + j;
          const char* va = (const char*)Vf + ((size_t)(b * 32 + (C >> 6))) * 8192 +
                           (((C >> 5) & 1) * 4 + (dim >> 4)) * 1024 +
                           ((dim & 15) + ((C >> 3) & 3) * 16) * 16 + (C & 7) * 2;
          vv[j] = bf2f(*(const unsigned short*)va);
        }
        o0 += pe * vv[0]; o1 += pe * vv[1]; o2 += pe * vv[2]; o3 += pe * vv[3];
      }
    }
    const float inv = 1.0f / lf;
    float4 r;
    r.x = o0 * inv; r.y = o1 * inv; r.z = o2 * inv; r.w = o3 * inv;
    *(float4*)(out + ((size_t)b * SEQ + q0 + row) * 64 + d0) = r;
  }
}

// ================================= launch =====================================
extern "C" void kernel_launch(void* const* d_in, const int* in_sizes, int n_in,
                              void* d_out, int out_size, void* d_ws,
                              size_t ws_size, hipStream_t stream) {
  const float* xq = (const float*)d_in[0];
  const float* xk = (const float*)d_in[1];
  const float* xv = (const float*)d_in[2];
  const float* Wq = (const float*)d_in[3];
  const float* bq = (const float*)d_in[4];
  const float* Wk = (const float*)d_in[5];
  const float* bk = (const float*)d_in[6];
  const float* Wv = (const float*)d_in[7];
  const float* bv = (const float*)d_in[8];
  float* out = (float*)d_out;

  // workspace (bf16): Qf 1MB, Kf 1MB, Vf 1MB, WTc 384KB (fragment-major layouts)
  unsigned short* Qf  = (unsigned short*)d_ws;
  unsigned short* Kf  = Qf + (size_t)NBATCH * SEQ * 64;
  unsigned short* Vf  = Kf + (size_t)NBATCH * SEQ * 64;
  unsigned short* WTc = Vf + (size_t)NBATCH * SEQ * 64;

  nprng::PCG64 g;
  nprng::pcg_seed_from_seedseq0(g);
  long long rows[3], cols[3];
  nprng::choice3_2048(g, rows);
  nprng::choice3_2048(g, cols);

  wtrans_kernel<<<96, 256, 0, stream>>>(Wq, Wk, Wv, WTc);

  proj_kernel<<<1536, 128, 0, stream>>>(xq, xk, xv, WTc, bq, bk, bv, Qf, Kf, Vf);

  dim3 agrid(SEQ / 16, NBATCH);
  attn_kernel<<<agrid, 256, 0, stream>>>(
      Qf, Kf, Vf, out, (int)rows[0], (int)cols[0], (int)rows[1], (int)cols[1],
      (int)rows[2], (int)cols[2]);
}

// Round 3
// 167.992 us; speedup vs baseline: 1.0014x; 1.0011x over previous
//
#include <hip/hip_runtime.h>
#include <cstdint>
#include <cstddef>
#include <math.h>

#define SEQ    2048
#define NBATCH 4
#define DIN    1024
#define DH     64

typedef __attribute__((ext_vector_type(8))) short  short8;   // 8 x bf16 (4 VGPRs)
typedef __attribute__((ext_vector_type(4))) float  floatx4;  // MFMA C/D

#define MFMA16(a, b, c) __builtin_amdgcn_mfma_f32_16x16x32_bf16((a), (b), (c), 0, 0, 0)

__device__ __forceinline__ unsigned short f2bf(float x) {
  unsigned u = __float_as_uint(x);
  return (unsigned short)((u + 0x8000u) >> 16);   // round-half-up; values finite
}
__device__ __forceinline__ float bf2f(unsigned short h) {
  return __uint_as_float(((unsigned)h) << 16);
}

// volatile-asm global loads: total order among themselves, defs can't be
// rematerialized or sunk -> the register double-buffer MUST stay allocated.
// (round-1/2 lesson: C++ loads + sched_barrier still collapsed to VGPR=44.)
template <int OFF>
__device__ __forceinline__ void gldx(floatx4 &d, unsigned long long a) {
  asm volatile("global_load_dwordx4 %0, %1, off offset:%2"
               : "=v"(d) : "v"(a), "n"(OFF));
}
template <int OFF>
__device__ __forceinline__ void gldw(short8 &d, unsigned long long a) {
  asm volatile("global_load_dwordx4 %0, %1, off offset:%2"
               : "=v"(d) : "v"(a), "n"(OFF));
}
#define WAITV(N) asm volatile("s_waitcnt vmcnt(" #N ")" ::: "memory")
#define SB()     __builtin_amdgcn_sched_barrier(0)

// ======================= host-side numpy RNG replication =======================
namespace nprng {

struct PCG64 {
  __uint128_t state, inc;
  bool has_uint32;
  uint32_t uinteger;
};

static inline void pcg_step(PCG64 &g) {
  const __uint128_t MULT =
      (((__uint128_t)0x2360ed051fc65da4ULL) << 64) | 0x4385df649fccf645ULL;
  g.state = g.state * MULT + g.inc;
}

static inline uint64_t pcg_output(const PCG64 &g) {
  uint64_t hi = (uint64_t)(g.state >> 64);
  uint64_t lo = (uint64_t)g.state;
  uint64_t x = hi ^ lo;
  unsigned rot = (unsigned)(g.state >> 122) & 63u;
  return (x >> rot) | (x << ((64u - rot) & 63u));
}

static inline uint64_t pcg_next64(PCG64 &g) { pcg_step(g); return pcg_output(g); }

static inline uint32_t pcg_next32(PCG64 &g) {
  if (g.has_uint32) { g.has_uint32 = false; return g.uinteger; }
  uint64_t n = pcg_next64(g);
  g.has_uint32 = true;
  g.uinteger = (uint32_t)(n >> 32);
  return (uint32_t)(n & 0xffffffffu);
}

static inline void pcg_seed_from_seedseq0(PCG64 &g) {
  const uint32_t MULT_A = 0x931e8875u;
  const uint32_t MULT_B = 0x58f38dedu;
  const uint32_t MIX_L  = 0xca01f9ddu;
  const uint32_t MIX_R  = 0x4973f715u;
  uint32_t hc = 0x43b0d7e5u;  // INIT_A
  uint32_t pool[4];
  for (int i = 0; i < 4; i++) {
    uint32_t v = 0u;
    v ^= hc; hc *= MULT_A; v *= hc; v ^= v >> 16;
    pool[i] = v;
  }
  for (int is = 0; is < 4; is++) {
    for (int id = 0; id < 4; id++) {
      if (is == id) continue;
      uint32_t h = pool[is];
      h ^= hc; hc *= MULT_A; h *= hc; h ^= h >> 16;
      uint32_t r = (pool[id] * MIX_L) ^ (h * MIX_R);
      r ^= r >> 16;
      pool[id] = r;
    }
  }
  uint32_t hb = 0x8b51f9ddu;  // INIT_B
  uint32_t w[8];
  for (int i = 0; i < 8; i++) {
    uint32_t v = pool[i & 3];
    v ^= hb; hb *= MULT_B; v *= hb; v ^= v >> 16;
    w[i] = v;
  }
  uint64_t sv[4];
  for (int k = 0; k < 4; k++)
    sv[k] = (uint64_t)w[2 * k] | ((uint64_t)w[2 * k + 1] << 32);
  __uint128_t initstate = (((__uint128_t)sv[0]) << 64) | sv[1];
  __uint128_t initseq   = (((__uint128_t)sv[2]) << 64) | sv[3];
  g.state = 0; g.inc = (initseq << 1) | 1;
  pcg_step(g);
  g.state += initstate;
  pcg_step(g);
  g.has_uint32 = false; g.uinteger = 0;
}

static inline uint32_t bounded32(PCG64 &g, uint32_t rng /*inclusive max*/) {
  if (rng == 0) return 0;
  const uint32_t rng_excl = rng + 1u;
  uint64_t m = (uint64_t)pcg_next32(g) * (uint64_t)rng_excl;
  uint32_t leftover = (uint32_t)m;
  if (leftover < rng_excl) {
    const uint32_t threshold = (uint32_t)(0xffffffffu - rng) % rng_excl;
    while (leftover < threshold) {
      m = (uint64_t)pcg_next32(g) * (uint64_t)rng_excl;
      leftover = (uint32_t)m;
    }
  }
  return (uint32_t)(m >> 32);
}

static inline void choice3_2048(PCG64 &g, long long idx[3]) {
  const int pop = 2048, sz = 3;
  uint64_t hs[4] = { (uint64_t)-1, (uint64_t)-1, (uint64_t)-1, (uint64_t)-1 };
  const uint64_t mask = 3;
  for (int j = pop - sz; j < pop; j++) {
    uint64_t val = (uint64_t)bounded32(g, (uint32_t)j);
    uint64_t loc = val & mask;
    while (hs[loc] != (uint64_t)-1 && hs[loc] != val) loc = (loc + 1) & mask;
    if (hs[loc] == (uint64_t)-1) {
      hs[loc] = val;
      idx[j - pop + sz] = (long long)val;
    } else {
      loc = (uint64_t)j & mask;
      while (hs[loc] != (uint64_t)-1) loc = (loc + 1) & mask;
      hs[loc] = (uint64_t)j;
      idx[j - pop + sz] = (long long)j;
    }
  }
  for (int i = 2; i >= 1; i--) {
    uint32_t j = bounded32(g, (uint32_t)i);
    long long t = idx[j]; idx[j] = idx[i]; idx[i] = t;
  }
}

}  // namespace nprng

// ==================== kernel 0: W -> fragment-major bf16 WTc ==================
// WTc layout (short8 units): u = ((((p*8+kc)*2 + nch)*4 + ks)*2 + f)*64 + l
// unit content, element j: W[(kc*128 + ks*32 + (l>>4)*8 + j)*64 + nch*32 + f*16 + (l&15)]
// i.e. exactly the MFMA B-fragment wave (col-half nch) lane l needs for (kc,ks,f).
__global__ __launch_bounds__(256) void wtrans_kernel(
    const float* __restrict__ Wq, const float* __restrict__ Wk,
    const float* __restrict__ Wv, unsigned short* __restrict__ WTc) {
  const int u = blockIdx.x * 256 + threadIdx.x;   // 0 .. 24575 short8 units
  const int l   = u & 63;
  const int fi  = (u >> 6) & 7;    // fi = ks*2 + f
  const int nch = (u >> 9) & 1;
  const int kc  = (u >> 10) & 7;
  const int p   = u >> 13;         // 0..2
  const int f   = fi & 1;
  const int ks  = fi >> 1;
  const float* W = (p == 0) ? Wq : (p == 1) ? Wk : Wv;
  const int n  = nch * 32 + f * 16 + (l & 15);
  const int k0 = kc * 128 + ks * 32 + ((l >> 4) * 8);
  short8 v;
#pragma unroll
  for (int j = 0; j < 8; j++) v[j] = (short)f2bf(W[(size_t)(k0 + j) * 64 + n]);
  *((short8*)WTc + u) = v;
}

// ======== projections: asm-pinned register-pipelined bf16 MFMA GEMM ===========
// grid 1536 x 128 thr (2 waves). Block = 16 rows x 64 cols; wave w owns
// col-half w*32. K=1024 in 8 chunks of 128; chunks k and k+1 are always in
// flight (16 volatile-asm dwordx4 loads each: 8 X from HBM, 8 W frags from
// L2-resident WTc). Per chunk: s_waitcnt vmcnt(16) [counted, never 0 until
// the tail] -> sched_barrier(0) [rule-18 fence: no cvt/MFMA hoists above the
// wait] -> consume -> re-issue chunk k+2 into the freed registers. All X
// offsets fit the 13-bit immediate (max 3984B): one base VGPR pair, no
// address VALU. 6 blocks/CU = 12 waves/CU, exactly one dispatch round.
__global__ __launch_bounds__(128, 3) void proj_kernel(
    const float* __restrict__ xq, const float* __restrict__ xk,
    const float* __restrict__ xv, const unsigned short* __restrict__ WTc,
    const float* __restrict__ bq, const float* __restrict__ bk,
    const float* __restrict__ bv,
    unsigned short* __restrict__ Qf, unsigned short* __restrict__ Kf,
    unsigned short* __restrict__ Vf) {
  const int bid  = blockIdx.x;
  const int proj = bid >> 9;               // 512 blocks per projection
  const int m0   = (bid & 511) << 4;       // row within proj (16-row block)
  const float* X    = (proj == 0) ? xq : (proj == 1) ? xk : xv;
  const float* bias = (proj == 0) ? bq : (proj == 1) ? bk : bv;

  const int tid  = threadIdx.x;
  const int w    = tid >> 6;               // col-half
  const int l    = tid & 63;
  const int quad = l >> 4;
  const int lx   = l & 15;

  const unsigned long long xab =
      (unsigned long long)(const void*)(X + (size_t)(m0 + lx) * DIN + quad * 8);
  const unsigned long long wab =
      (unsigned long long)(const void*)((const short8*)WTc +
                                        ((size_t)(proj * 16 + w)) * 512 + l);
  // W: chunk kc at wab + kc*16384 B; frag i at +i*1024 B (split 4+4 via +4096).

  floatx4 acc0 = {0.f, 0.f, 0.f, 0.f}, acc1 = acc0;
  floatx4 xa[8], xb[8];
  short8  wa[8], wb[8];

  auto CHUNK = [&](const floatx4* xr, const short8* wr) {
#pragma unroll
    for (int ks = 0; ks < 4; ks++) {
      const floatx4 f0 = xr[2 * ks], f1 = xr[2 * ks + 1];
      short8 a;
      a[0] = f2bf(f0[0]); a[1] = f2bf(f0[1]); a[2] = f2bf(f0[2]); a[3] = f2bf(f0[3]);
      a[4] = f2bf(f1[0]); a[5] = f2bf(f1[1]); a[6] = f2bf(f1[2]); a[7] = f2bf(f1[3]);
      acc0 = MFMA16(a, wr[2 * ks],     acc0);
      acc1 = MFMA16(a, wr[2 * ks + 1], acc1);
    }
  };

#define STAGEX(KC, buf)                                                        \
  gldx<(KC)*512 +   0>(buf[0], xab); gldx<(KC)*512 +  16>(buf[1], xab);        \
  gldx<(KC)*512 + 128>(buf[2], xab); gldx<(KC)*512 + 144>(buf[3], xab);        \
  gldx<(KC)*512 + 256>(buf[4], xab); gldx<(KC)*512 + 272>(buf[5], xab);        \
  gldx<(KC)*512 + 384>(buf[6], xab); gldx<(KC)*512 + 400>(buf[7], xab)

#define STAGEW(KC, buf)                                                        \
  { const unsigned long long p0 = wab + (KC) * 16384ull;                       \
    const unsigned long long p1 = p0 + 4096ull;                                \
    gldw<   0>(buf[0], p0); gldw<1024>(buf[1], p0);                            \
    gldw<2048>(buf[2], p0); gldw<3072>(buf[3], p0);                            \
    gldw<   0>(buf[4], p1); gldw<1024>(buf[5], p1);                            \
    gldw<2048>(buf[6], p1); gldw<3072>(buf[7], p1); }

  // prologue: chunks 0 and 1 in flight (32 loads outstanding)
  STAGEX(0, xa); STAGEW(0, wa);
  STAGEX(1, xb); STAGEW(1, wb);

  WAITV(16); SB(); CHUNK(xa, wa); STAGEX(2, xa); STAGEW(2, wa); SB();
  WAITV(16); SB(); CHUNK(xb, wb); STAGEX(3, xb); STAGEW(3, wb); SB();
  WAITV(16); SB(); CHUNK(xa, wa); STAGEX(4, xa); STAGEW(4, wa); SB();
  WAITV(16); SB(); CHUNK(xb, wb); STAGEX(5, xb); STAGEW(5, wb); SB();
  WAITV(16); SB(); CHUNK(xa, wa); STAGEX(6, xa); STAGEW(6, wa); SB();
  WAITV(16); SB(); CHUNK(xb, wb); STAGEX(7, xb); STAGEW(7, wb); SB();
  WAITV(16); SB(); CHUNK(xa, wa); SB();
  WAITV(0);  SB(); CHUNK(xb, wb);

#undef STAGEX
#undef STAGEW

  // ---- epilogue: stage 16x64 tile (+bias) in LDS, emit fragment layouts ----
  __shared__ float Cs[16][68];
  const float bb0 = bias[w * 32 + lx], bb1 = bias[w * 32 + 16 + lx];
#pragma unroll
  for (int i = 0; i < 4; i++) {
    Cs[quad * 4 + i][w * 32 + lx]      = acc0[i] + bb0;
    Cs[quad * 4 + i][w * 32 + 16 + lx] = acc1[i] + bb1;
  }
  __syncthreads();

  const int b_  = m0 >> 11;                // batch
  const int s0  = m0 & 2047;               // seq offset within batch
  const int ll  = tid & 63, lxx = ll & 15, qq = ll >> 4;

  if (proj == 0) {
    // Qf: per (b, qt) 2048 B: frag s(2) x lane(64) x 16 B
    const int s = tid >> 6;
    short8 v;
#pragma unroll
    for (int j = 0; j < 8; j++) v[j] = (short)f2bf(Cs[lxx][s * 32 + qq * 8 + j]);
    char* dst = (char*)Qf + ((size_t)(b_ * 128 + (s0 >> 4))) * 2048 + s * 1024 + ll * 16;
    *(short8*)dst = v;
  } else if (proj == 1) {
    // Kf: per (b, t=64-row tile) 8192 B: frag (c*2+s); this block owns one c.
    const int s = tid >> 6;
    const int c = (s0 >> 4) & 3;
    short8 v;
#pragma unroll
    for (int j = 0; j < 8; j++) v[j] = (short)f2bf(Cs[lxx][s * 32 + qq * 8 + j]);
    char* dst = (char*)Kf + ((size_t)(b_ * 32 + (s0 >> 6))) * 8192 + (c * 2 + s) * 1024 + ll * 16;
    *(short8*)dst = v;
  } else {
    // Vf: frag (sf*4+c), lane lv -> V[t*64+sf*32+(lv>>4)*8+j][16c+(lv&15)].
    // A frag spans 32 seq rows; this 16-row block fills lane half h of 4 frags.
    const int h  = (s0 >> 4) & 1;          // which 16-row half of the 32-row span
    const int sf = (s0 >> 5) & 1;
    const int c  = tid >> 5;               // 0..3
    const int lv = h * 32 + (tid & 31);    // destination lane within frag
    const int q2 = (lv >> 4) & 1;          // row-octet within this block
    const int lxv = lv & 15;
    short8 v;
#pragma unroll
    for (int j = 0; j < 8; j++) v[j] = (short)f2bf(Cs[q2 * 8 + j][c * 16 + lxv]);
    char* dst = (char*)Vf + ((size_t)(b_ * 32 + (s0 >> 6))) * 8192 + (sf * 4 + c) * 1024 + lv * 16;
    *(short8*)dst = v;
  }
}

// ============ flash attention: fragment-major direct loads, 1 barrier =========
// grid (128, 4), 256 threads (4 waves). Block = 16 q-rows; wave w processes
// key-tiles t = w, w+4, ... with independent online-softmax state; merged once.
// All Q/K/V fragment loads are per-wave LINEAR global reads (chunk + lane*16):
// perfect coalescing, no LDS staging, no barriers, no bank conflicts.
__global__ __launch_bounds__(256, 2) void attn_kernel(
    const unsigned short* __restrict__ Qf, const unsigned short* __restrict__ Kf,
    const unsigned short* __restrict__ Vf, float* __restrict__ out,
    int R0, int C0, int R1, int C1, int R2, int C2) {
  const int b    = blockIdx.y;
  const int bx   = blockIdx.x;
  const int qi   = (bx & 1) ? (127 - (bx >> 1)) : (bx >> 1);  // heavy/light pairing
  const int q0   = qi * 16;
  const int tid  = threadIdx.x;
  const int w    = tid >> 6;
  const int l    = tid & 63;
  const int quad = l >> 4;
  const int lx   = l & 15;

  __shared__ unsigned short Ps[4][16][72];
  __shared__ float Os[4][16][64];
  __shared__ float mS[4][16], lS[4][16];
  __shared__ float lgS[3];
  __shared__ int   lgF[3];

  const char* Qc = (const char*)Qf + ((size_t)(b * 128 + qi)) * 2048 + l * 16;
  const short8 aq0 = *(const short8*)Qc;
  const short8 aq1 = *(const short8*)(Qc + 1024);

  floatx4 O[4];
  float m_i[4], l_i[4];
#pragma unroll
  for (int c = 0; c < 4; c++) O[c] = (floatx4){0.f, 0.f, 0.f, 0.f};
#pragma unroll
  for (int i = 0; i < 4; i++) { m_i[i] = -INFINITY; l_i[i] = 0.f; }

  const int T = (q0 + 79) >> 6;   // key-tiles needed (64 keys each)

  for (int t = w; t < T; t += 4) {
    const int k0 = t << 6;
    const bool mT = (t == T - 1);

    const char* Kc = (const char*)Kf + ((size_t)(b * 32 + t)) * 8192 + l * 16;
    const char* Vc = (const char*)Vf + ((size_t)(b * 32 + t)) * 8192 + l * 16;
    short8 kf[8], vf[8];
#pragma unroll
    for (int f = 0; f < 8; f++) {
      kf[f] = *(const short8*)(Kc + f * 1024);
      vf[f] = *(const short8*)(Vc + f * 1024);
    }

    floatx4 sc[4];
    __builtin_amdgcn_s_setprio(1);
#pragma unroll
    for (int c = 0; c < 4; c++) {
      sc[c] = (floatx4){0.f, 0.f, 0.f, 0.f};
      sc[c] = MFMA16(aq0, kf[2 * c], sc[c]);
      sc[c] = MFMA16(aq1, kf[2 * c + 1], sc[c]);
    }
    __builtin_amdgcn_s_setprio(0);

    float mt[4], al[4];
#pragma unroll
    for (int i = 0; i < 4; i++) {
      const int rowg = q0 + quad * 4 + i;
      float vmax = -INFINITY;
#pragma unroll
      for (int c = 0; c < 4; c++) {
        float v = sc[c][i] * 0.125f;
        if (mT && (k0 + 16 * c + lx) > rowg) v = -INFINITY;
        sc[c][i] = v;
        vmax = fmaxf(vmax, v);
      }
      mt[i] = vmax;
    }
#pragma unroll
    for (int i = 0; i < 4; i++) {
#pragma unroll
      for (int off = 8; off >= 1; off >>= 1)
        mt[i] = fmaxf(mt[i], __shfl_xor(mt[i], off));
      const float mn = fmaxf(m_i[i], mt[i]);
      al[i] = __expf(m_i[i] - mn);
      m_i[i] = mn;
      float s = 0.f;
#pragma unroll
      for (int c = 0; c < 4; c++) {
        float p = __expf(sc[c][i] - mn);
        Ps[w][quad * 4 + i][16 * c + lx] = f2bf(p);
        s += p;
      }
#pragma unroll
      for (int off = 8; off >= 1; off >>= 1) s += __shfl_xor(s, off);
      l_i[i] = l_i[i] * al[i] + s;
    }
#pragma unroll
    for (int c = 0; c < 4; c++)
#pragma unroll
      for (int i = 0; i < 4; i++) O[c][i] *= al[i];
    asm volatile("" ::: "memory");  // keep ds_reads below the ds_writes above
    const short8 pf0 = *(const short8*)&Ps[w][lx][quad * 8];
    const short8 pf1 = *(const short8*)&Ps[w][lx][32 + quad * 8];
    __builtin_amdgcn_s_setprio(1);
#pragma unroll
    for (int c = 0; c < 4; c++) {
      O[c] = MFMA16(pf0, vf[c],     O[c]);
      O[c] = MFMA16(pf1, vf[4 + c], O[c]);
    }
    __builtin_amdgcn_s_setprio(0);
  }

  // deposit per-wave state
  if (lx == 0) {
#pragma unroll
    for (int i = 0; i < 4; i++) {
      mS[w][quad * 4 + i] = m_i[i];
      lS[w][quad * 4 + i] = l_i[i];
    }
  }
#pragma unroll
  for (int c = 0; c < 4; c++)
#pragma unroll
    for (int i = 0; i < 4; i++) Os[w][quad * 4 + i][16 * c + lx] = O[c][i];

  // wave 0: logits for global pairs above the diagonal (lane l owns dim d=l)
  if (w == 0) {
#pragma unroll
    for (int p = 0; p < 3; p++) {
      const int R = (p == 0) ? R0 : (p == 1) ? R1 : R2;
      const int C = (p == 0) ? C0 : (p == 1) ? C1 : C2;
      const int act = (R >= q0 && R < q0 + 16 && C > R);
      float d = 0.f;
      if (act) {
        const int dd = l;
        const char* qa = (const char*)Qf + ((size_t)(b * 128 + (R >> 4))) * 2048 +
                         (dd >> 5) * 1024 + ((R & 15) + ((dd >> 3) & 3) * 16) * 16 + (dd & 7) * 2;
        const char* ka = (const char*)Kf + ((size_t)(b * 32 + (C >> 6))) * 8192 +
                         (((C >> 4) & 3) * 2 + (dd >> 5)) * 1024 +
                         ((C & 15) + ((dd >> 3) & 3) * 16) * 16 + (dd & 7) * 2;
        d = bf2f(*(const unsigned short*)qa) * bf2f(*(const unsigned short*)ka);
#pragma unroll
        for (int off = 32; off >= 1; off >>= 1) d += __shfl_xor(d, off);
        d *= 0.125f;
      }
      if (l == 0) { lgF[p] = act; lgS[p] = d; }
    }
  }
  __syncthreads();

  // merge the 4 wave states (+ pair fixups), normalize, store
  {
    const int row = tid >> 4;          // 0..15
    const int d0  = (tid & 15) * 4;    // 0..60
    const int Rs[3] = {R0, R1, R2};
    const int Cs3[3] = {C0, C1, C2};

    float mf = -INFINITY;
#pragma unroll
    for (int w4 = 0; w4 < 4; w4++) mf = fmaxf(mf, mS[w4][row]);
#pragma unroll
    for (int p = 0; p < 3; p++)
      if (lgF[p] && (Rs[p] - q0) == row) mf = fmaxf(mf, lgS[p]);

    float lf = 0.f;
    float o0 = 0.f, o1 = 0.f, o2 = 0.f, o3 = 0.f;
#pragma unroll
    for (int w4 = 0; w4 < 4; w4++) {
      const float a = __expf(mS[w4][row] - mf);
      lf += a * lS[w4][row];
      const float* op = &Os[w4][row][d0];
      o0 += a * op[0]; o1 += a * op[1]; o2 += a * op[2]; o3 += a * op[3];
    }
#pragma unroll
    for (int p = 0; p < 3; p++) {
      if (lgF[p] && (Rs[p] - q0) == row) {
        const float pe = __expf(lgS[p] - mf);
        lf += pe;
        const int C = Cs3[p];
        float vv[4];
#pragma unroll
        for (int j = 0; j < 4; j++) {
          const int dim = d0 + j;
          const char* va = (const char*)Vf + ((size_t)(b * 32 + (C >> 6))) * 8192 +
                           (((C >> 5) & 1) * 4 + (dim >> 4)) * 1024 +
                           ((dim & 15) + ((C >> 3) & 3) * 16) * 16 + (C & 7) * 2;
          vv[j] = bf2f(*(const unsigned short*)va);
        }
        o0 += pe * vv[0]; o1 += pe * vv[1]; o2 += pe * vv[2]; o3 += pe * vv[3];
      }
    }
    const float inv = 1.0f / lf;
    float4 r;
    r.x = o0 * inv; r.y = o1 * inv; r.z = o2 * inv; r.w = o3 * inv;
    *(float4*)(out + ((size_t)b * SEQ + q0 + row) * 64 + d0) = r;
  }
}

// ================================= launch =====================================
extern "C" void kernel_launch(void* const* d_in, const int* in_sizes, int n_in,
                              void* d_out, int out_size, void* d_ws,
                              size_t ws_size, hipStream_t stream) {
  const float* xq = (const float*)d_in[0];
  const float* xk = (const float*)d_in[1];
  const float* xv = (const float*)d_in[2];
  const float* Wq = (const float*)d_in[3];
  const float* bq = (const float*)d_in[4];
  const float* Wk = (const float*)d_in[5];
  const float* bk = (const float*)d_in[6];
  const float* Wv = (const float*)d_in[7];
  const float* bv = (const float*)d_in[8];
  float* out = (float*)d_out;

  // workspace (bf16): Qf 1MB, Kf 1MB, Vf 1MB, WTc 384KB (fragment-major layouts)
  unsigned short* Qf  = (unsigned short*)d_ws;
  unsigned short* Kf  = Qf + (size_t)NBATCH * SEQ * 64;
  unsigned short* Vf  = Kf + (size_t)NBATCH * SEQ * 64;
  unsigned short* WTc = Vf + (size_t)NBATCH * SEQ * 64;

  nprng::PCG64 g;
  nprng::pcg_seed_from_seedseq0(g);
  long long rows[3], cols[3];
  nprng::choice3_2048(g, rows);
  nprng::choice3_2048(g, cols);

  wtrans_kernel<<<96, 256, 0, stream>>>(Wq, Wk, Wv, WTc);

  proj_kernel<<<1536, 128, 0, stream>>>(xq, xk, xv, WTc, bq, bk, bv, Qf, Kf, Vf);

  dim3 agrid(SEQ / 16, NBATCH);
  attn_kernel<<<agrid, 256, 0, stream>>>(
      Qf, Kf, Vf, out, (int)rows[0], (int)cols[0], (int)rows[1], (int)cols[1],
      (int)rows[2], (int)cols[2]);
}

// Round 4
// 154.991 us; speedup vs baseline: 1.0854x; 1.0839x over previous
//
#include <hip/hip_runtime.h>
#include <cstdint>
#include <cstddef>
#include <math.h>

#define SEQ    2048
#define NBATCH 4
#define DIN    1024
#define DH     64

typedef __attribute__((ext_vector_type(8))) short  short8;   // 8 x bf16 (4 VGPRs)
typedef __attribute__((ext_vector_type(4))) float  floatx4;  // MFMA C/D

#define MFMA16(a, b, c) __builtin_amdgcn_mfma_f32_16x16x32_bf16((a), (b), (c), 0, 0, 0)

__device__ __forceinline__ unsigned short f2bf(float x) {
  unsigned u = __float_as_uint(x);
  return (unsigned short)((u + 0x8000u) >> 16);   // round-half-up; values finite
}
__device__ __forceinline__ float bf2f(unsigned short h) {
  return __uint_as_float(((unsigned)h) << 16);
}

// async global->LDS DMA (no dest VGPR); deposits at lds_base + lane*size.
__device__ __forceinline__ void async_cp4(const void* g, void* l) {
  __builtin_amdgcn_global_load_lds(
      (const __attribute__((address_space(1))) void*)g,
      (__attribute__((address_space(3))) void*)l, 4, 0, 0);
}

// volatile-asm W-fragment load: ordered among volatile asms, cannot be sunk.
template <int OFF>
__device__ __forceinline__ void gldw(short8 &d, unsigned long long a) {
  asm volatile("global_load_dwordx4 %0, %1, off offset:%2"
               : "=v"(d) : "v"(a), "n"(OFF));
}
#define WAITV(N) asm volatile("s_waitcnt vmcnt(" #N ")" ::: "memory")
#define SB()     __builtin_amdgcn_sched_barrier(0)
#define BAR()    __builtin_amdgcn_s_barrier()

// ======================= host-side numpy RNG replication =======================
namespace nprng {

struct PCG64 {
  __uint128_t state, inc;
  bool has_uint32;
  uint32_t uinteger;
};

static inline void pcg_step(PCG64 &g) {
  const __uint128_t MULT =
      (((__uint128_t)0x2360ed051fc65da4ULL) << 64) | 0x4385df649fccf645ULL;
  g.state = g.state * MULT + g.inc;
}

static inline uint64_t pcg_output(const PCG64 &g) {
  uint64_t hi = (uint64_t)(g.state >> 64);
  uint64_t lo = (uint64_t)g.state;
  uint64_t x = hi ^ lo;
  unsigned rot = (unsigned)(g.state >> 122) & 63u;
  return (x >> rot) | (x << ((64u - rot) & 63u));
}

static inline uint64_t pcg_next64(PCG64 &g) { pcg_step(g); return pcg_output(g); }

static inline uint32_t pcg_next32(PCG64 &g) {
  if (g.has_uint32) { g.has_uint32 = false; return g.uinteger; }
  uint64_t n = pcg_next64(g);
  g.has_uint32 = true;
  g.uinteger = (uint32_t)(n >> 32);
  return (uint32_t)(n & 0xffffffffu);
}

static inline void pcg_seed_from_seedseq0(PCG64 &g) {
  const uint32_t MULT_A = 0x931e8875u;
  const uint32_t MULT_B = 0x58f38dedu;
  const uint32_t MIX_L  = 0xca01f9ddu;
  const uint32_t MIX_R  = 0x4973f715u;
  uint32_t hc = 0x43b0d7e5u;  // INIT_A
  uint32_t pool[4];
  for (int i = 0; i < 4; i++) {
    uint32_t v = 0u;
    v ^= hc; hc *= MULT_A; v *= hc; v ^= v >> 16;
    pool[i] = v;
  }
  for (int is = 0; is < 4; is++) {
    for (int id = 0; id < 4; id++) {
      if (is == id) continue;
      uint32_t h = pool[is];
      h ^= hc; hc *= MULT_A; h *= hc; h ^= h >> 16;
      uint32_t r = (pool[id] * MIX_L) ^ (h * MIX_R);
      r ^= r >> 16;
      pool[id] = r;
    }
  }
  uint32_t hb = 0x8b51f9ddu;  // INIT_B
  uint32_t w[8];
  for (int i = 0; i < 8; i++) {
    uint32_t v = pool[i & 3];
    v ^= hb; hb *= MULT_B; v *= hb; v ^= v >> 16;
    w[i] = v;
  }
  uint64_t sv[4];
  for (int k = 0; k < 4; k++)
    sv[k] = (uint64_t)w[2 * k] | ((uint64_t)w[2 * k + 1] << 32);
  __uint128_t initstate = (((__uint128_t)sv[0]) << 64) | sv[1];
  __uint128_t initseq   = (((__uint128_t)sv[2]) << 64) | sv[3];
  g.state = 0; g.inc = (initseq << 1) | 1;
  pcg_step(g);
  g.state += initstate;
  pcg_step(g);
  g.has_uint32 = false; g.uinteger = 0;
}

static inline uint32_t bounded32(PCG64 &g, uint32_t rng /*inclusive max*/) {
  if (rng == 0) return 0;
  const uint32_t rng_excl = rng + 1u;
  uint64_t m = (uint64_t)pcg_next32(g) * (uint64_t)rng_excl;
  uint32_t leftover = (uint32_t)m;
  if (leftover < rng_excl) {
    const uint32_t threshold = (uint32_t)(0xffffffffu - rng) % rng_excl;
    while (leftover < threshold) {
      m = (uint64_t)pcg_next32(g) * (uint64_t)rng_excl;
      leftover = (uint32_t)m;
    }
  }
  return (uint32_t)(m >> 32);
}

static inline void choice3_2048(PCG64 &g, long long idx[3]) {
  const int pop = 2048, sz = 3;
  uint64_t hs[4] = { (uint64_t)-1, (uint64_t)-1, (uint64_t)-1, (uint64_t)-1 };
  const uint64_t mask = 3;
  for (int j = pop - sz; j < pop; j++) {
    uint64_t val = (uint64_t)bounded32(g, (uint32_t)j);
    uint64_t loc = val & mask;
    while (hs[loc] != (uint64_t)-1 && hs[loc] != val) loc = (loc + 1) & mask;
    if (hs[loc] == (uint64_t)-1) {
      hs[loc] = val;
      idx[j - pop + sz] = (long long)val;
    } else {
      loc = (uint64_t)j & mask;
      while (hs[loc] != (uint64_t)-1) loc = (loc + 1) & mask;
      hs[loc] = (uint64_t)j;
      idx[j - pop + sz] = (long long)j;
    }
  }
  for (int i = 2; i >= 1; i--) {
    uint32_t j = bounded32(g, (uint32_t)i);
    long long t = idx[j]; idx[j] = idx[i]; idx[i] = t;
  }
}

}  // namespace nprng

// ==================== kernel 0: W -> fragment-major bf16 WTc ==================
// WTc layout (short8 units): u = ((((p*8+kc)*2 + nch)*4 + ks)*2 + f)*64 + l
// unit content, element j: W[(kc*128 + ks*32 + (l>>4)*8 + j)*64 + nch*32 + f*16 + (l&15)]
// i.e. exactly the MFMA B-fragment wave (col-half nch) lane l needs for (kc,ks,f).
__global__ __launch_bounds__(256) void wtrans_kernel(
    const float* __restrict__ Wq, const float* __restrict__ Wk,
    const float* __restrict__ Wv, unsigned short* __restrict__ WTc) {
  const int u = blockIdx.x * 256 + threadIdx.x;   // 0 .. 24575 short8 units
  const int l   = u & 63;
  const int fi  = (u >> 6) & 7;    // fi = ks*2 + f
  const int nch = (u >> 9) & 1;
  const int kc  = (u >> 10) & 7;
  const int p   = u >> 13;         // 0..2
  const int f   = fi & 1;
  const int ks  = fi >> 1;
  const float* W = (p == 0) ? Wq : (p == 1) ? Wk : Wv;
  const int n  = nch * 32 + f * 16 + (l & 15);
  const int k0 = kc * 128 + ks * 32 + ((l >> 4) * 8);
  short8 v;
#pragma unroll
  for (int j = 0; j < 8; j++) v[j] = (short)f2bf(W[(size_t)(k0 + j) * 64 + n]);
  *((short8*)WTc + u) = v;
}

// ======== projections: LDS-staged X + reg W, counted-vmcnt barrier pipeline ===
// grid 768 x 256 thr (4 waves). Block = 32 rows of the concatenated 24576-row
// [q;k;v] input; wave w: row-half (w&1), col-half (w>>1). K=1024 in 8 chunks.
// X is DMA'd ONCE per block into a double-buffered LDS tile (132-pad f32,
// conflict-free reads, proven in round 0); W fragments come straight from the
// L2-resident fragment-major WTc into registers (volatile-asm, double-buffered).
// Per chunk: stage(k+1)=24 VMEM ops -> s_waitcnt vmcnt(24) [chunk k landed,
// k+1 stays IN FLIGHT across the barrier - the T4 counted-vmcnt pattern, never
// a vmcnt(0) drain] -> sched_barrier(0) -> s_barrier -> consume(k) -> s_barrier
// (WAR: all waves done reading buf before it is restaged). LDS 33 KB (W no
// longer staged; epilogue Cs aliases buf0), 12 waves/CU, one dispatch round.
__global__ __launch_bounds__(256, 3) void proj_kernel(
    const float* __restrict__ xq, const float* __restrict__ xk,
    const float* __restrict__ xv, const unsigned short* __restrict__ WTc,
    const float* __restrict__ bq, const float* __restrict__ bk,
    const float* __restrict__ bv,
    unsigned short* __restrict__ Qf, unsigned short* __restrict__ Kf,
    unsigned short* __restrict__ Vf) {
  const int m0g  = blockIdx.x * 32;        // 0..24544
  const int proj = m0g >> 13;              // 0,1,2
  const int m0   = m0g & 8191;             // row within proj
  const float* X    = (proj == 0) ? xq : (proj == 1) ? xk : xv;
  const float* bias = (proj == 0) ? bq : (proj == 1) ? bk : bv;

  const int tid  = threadIdx.x;
  const int w    = tid >> 6;
  const int l    = tid & 63;
  const int quad = l >> 4;
  const int lx   = l & 15;
  const int mr   = (w & 1) * 16;           // wave's row half
  const int nc   = (w >> 1) * 32;          // wave's col half

  // LDS: X dbuf 2 x 16896 B (32 rows x 132 f32). Epilogue Cs aliases buf0.
  __shared__ __align__(16) char LDSbuf[2 * 16896];

  const float* Xblk = X + (size_t)m0 * DIN;
  const unsigned long long wab =
      (unsigned long long)(const void*)((const short8*)WTc +
                                        ((size_t)(proj * 16 + (w >> 1))) * 512 + l);
  // W chunk kc at wab + kc*16384 B; frag i at +i*1024 B (4+4 split via +4096).

  floatx4 acc0 = {0.f, 0.f, 0.f, 0.f}, acc1 = acc0;
  short8  wa[8], wb[8];

  // stage chunk kc: X rows 8w..8w+7 -> LDS buf (16 cp4), W frags -> reg buf (8)
#define STAGE(KC, XBUF, WBUF)                                                  \
  {                                                                            \
    float* Xs = (float*)(LDSbuf + (XBUF) * 16896);                             \
    _Pragma("unroll")                                                          \
    for (int i = 0; i < 8; i++) {                                              \
      const int r = 8 * w + i;                                                 \
      const float* g = Xblk + (size_t)r * DIN + (KC) * 128;                    \
      async_cp4(g + l,      &Xs[r * 132]);                                     \
      async_cp4(g + 64 + l, &Xs[r * 132 + 64]);                                \
    }                                                                          \
    const unsigned long long p0 = wab + (KC) * 16384ull;                       \
    const unsigned long long p1 = p0 + 4096ull;                                \
    gldw<   0>(WBUF[0], p0); gldw<1024>(WBUF[1], p0);                          \
    gldw<2048>(WBUF[2], p0); gldw<3072>(WBUF[3], p0);                          \
    gldw<   0>(WBUF[4], p1); gldw<1024>(WBUF[5], p1);                          \
    gldw<2048>(WBUF[6], p1); gldw<3072>(WBUF[7], p1);                          \
  }

#define CONSUME(XBUF, WBUF)                                                    \
  {                                                                            \
    const float* Xs = (const float*)(LDSbuf + (XBUF) * 16896);                 \
    _Pragma("unroll")                                                          \
    for (int ks = 0; ks < 4; ks++) {                                           \
      const float* ap = &Xs[(mr + lx) * 132 + ks * 32 + quad * 8];             \
      const float4 f0 = *(const float4*)ap;                                    \
      const float4 f1 = *(const float4*)(ap + 4);                              \
      short8 a;                                                                \
      a[0] = f2bf(f0.x); a[1] = f2bf(f0.y); a[2] = f2bf(f0.z); a[3] = f2bf(f0.w); \
      a[4] = f2bf(f1.x); a[5] = f2bf(f1.y); a[6] = f2bf(f1.z); a[7] = f2bf(f1.w); \
      acc0 = MFMA16(a, WBUF[2 * ks],     acc0);                                \
      acc1 = MFMA16(a, WBUF[2 * ks + 1], acc1);                                \
    }                                                                          \
  }

  STAGE(0, 0, wa);
  STAGE(1, 1, wb);
  WAITV(24); SB(); BAR(); CONSUME(0, wa); BAR();   // chunk 0
  STAGE(2, 0, wa);
  WAITV(24); SB(); BAR(); CONSUME(1, wb); BAR();   // chunk 1
  STAGE(3, 1, wb);
  WAITV(24); SB(); BAR(); CONSUME(0, wa); BAR();   // chunk 2
  STAGE(4, 0, wa);
  WAITV(24); SB(); BAR(); CONSUME(1, wb); BAR();   // chunk 3
  STAGE(5, 1, wb);
  WAITV(24); SB(); BAR(); CONSUME(0, wa); BAR();   // chunk 4
  STAGE(6, 0, wa);
  WAITV(24); SB(); BAR(); CONSUME(1, wb); BAR();   // chunk 5
  STAGE(7, 1, wb);
  WAITV(24); SB(); BAR(); CONSUME(0, wa); BAR();   // chunk 6
  WAITV(0);  SB(); BAR(); CONSUME(1, wb);          // chunk 7 (tail drain ok)

#undef STAGE
#undef CONSUME

  // ---- epilogue: stage 32x64 tile (+bias) in LDS (aliases buf0: dead after
  // chunk-6's closing barrier), emit attn fragment layouts ----
  float (*Cs)[68] = (float(*)[68])LDSbuf;  // 32 x 68 f32 = 8704 B
  const float bb0 = bias[nc + lx], bb1 = bias[nc + 16 + lx];
#pragma unroll
  for (int i = 0; i < 4; i++) {
    Cs[mr + quad * 4 + i][nc + lx]      = acc0[i] + bb0;
    Cs[mr + quad * 4 + i][nc + 16 + lx] = acc1[i] + bb1;
  }
  __syncthreads();

  const int bq_ = m0 >> 11;                // batch
  const int s0  = m0 & 2047;               // seq offset within batch
  if (proj == 0) {
    // Q: two 16-row tiles, frag s, lane ll
    const int ti = tid >> 7, s = (tid >> 6) & 1, ll = tid & 63;
    const int lxx = ll & 15, qq = ll >> 4;
    short8 v;
#pragma unroll
    for (int j = 0; j < 8; j++) v[j] = (short)f2bf(Cs[ti * 16 + lxx][s * 32 + qq * 8 + j]);
    char* dst = (char*)Qf + ((size_t)(bq_ * 128 + (s0 >> 4) + ti)) * 2048 + s * 1024 + ll * 16;
    *(short8*)dst = v;
  } else if (proj == 1) {
    // K: half of a 64-row tile -> frags (c0+ci, s)
    const int ci = tid >> 7, s = (tid >> 6) & 1, ll = tid & 63;
    const int lxx = ll & 15, qq = ll >> 4;
    const int c = ((s0 >> 4) & 3) + ci;
    short8 v;
#pragma unroll
    for (int j = 0; j < 8; j++) v[j] = (short)f2bf(Cs[ci * 16 + lxx][s * 32 + qq * 8 + j]);
    char* dst = (char*)Kf + ((size_t)(bq_ * 32 + (s0 >> 6))) * 8192 + (c * 2 + s) * 1024 + ll * 16;
    *(short8*)dst = v;
  } else {
    // V: s-half of a 64-row tile -> frags (sh, c=0..3); lane gathers 8 seq rows
    const int c = tid >> 6, ll = tid & 63;
    const int lxx = ll & 15, qq = ll >> 4;
    const int sh = (s0 >> 5) & 1;
    short8 v;
#pragma unroll
    for (int j = 0; j < 8; j++) v[j] = (short)f2bf(Cs[qq * 8 + j][c * 16 + lxx]);
    char* dst = (char*)Vf + ((size_t)(bq_ * 32 + (s0 >> 6))) * 8192 + (sh * 4 + c) * 1024 + ll * 16;
    *(short8*)dst = v;
  }
}

// ============ flash attention: fragment-major direct loads, 1 barrier =========
// grid (128, 4), 256 threads (4 waves). Block = 16 q-rows; wave w processes
// key-tiles t = w, w+4, ... with independent online-softmax state; merged once.
// All Q/K/V fragment loads are per-wave LINEAR global reads (chunk + lane*16):
// perfect coalescing, no LDS staging, no barriers, no bank conflicts.
__global__ __launch_bounds__(256, 2) void attn_kernel(
    const unsigned short* __restrict__ Qf, const unsigned short* __restrict__ Kf,
    const unsigned short* __restrict__ Vf, float* __restrict__ out,
    int R0, int C0, int R1, int C1, int R2, int C2) {
  const int b    = blockIdx.y;
  const int bx   = blockIdx.x;
  const int qi   = (bx & 1) ? (127 - (bx >> 1)) : (bx >> 1);  // heavy/light pairing
  const int q0   = qi * 16;
  const int tid  = threadIdx.x;
  const int w    = tid >> 6;
  const int l    = tid & 63;
  const int quad = l >> 4;
  const int lx   = l & 15;

  __shared__ unsigned short Ps[4][16][72];
  __shared__ float Os[4][16][64];
  __shared__ float mS[4][16], lS[4][16];
  __shared__ float lgS[3];
  __shared__ int   lgF[3];

  const char* Qc = (const char*)Qf + ((size_t)(b * 128 + qi)) * 2048 + l * 16;
  const short8 aq0 = *(const short8*)Qc;
  const short8 aq1 = *(const short8*)(Qc + 1024);

  floatx4 O[4];
  float m_i[4], l_i[4];
#pragma unroll
  for (int c = 0; c < 4; c++) O[c] = (floatx4){0.f, 0.f, 0.f, 0.f};
#pragma unroll
  for (int i = 0; i < 4; i++) { m_i[i] = -INFINITY; l_i[i] = 0.f; }

  const int T = (q0 + 79) >> 6;   // key-tiles needed (64 keys each)

  for (int t = w; t < T; t += 4) {
    const int k0 = t << 6;
    const bool mT = (t == T - 1);

    const char* Kc = (const char*)Kf + ((size_t)(b * 32 + t)) * 8192 + l * 16;
    const char* Vc = (const char*)Vf + ((size_t)(b * 32 + t)) * 8192 + l * 16;
    short8 kf[8], vf[8];
#pragma unroll
    for (int f = 0; f < 8; f++) {
      kf[f] = *(const short8*)(Kc + f * 1024);
      vf[f] = *(const short8*)(Vc + f * 1024);
    }

    floatx4 sc[4];
    __builtin_amdgcn_s_setprio(1);
#pragma unroll
    for (int c = 0; c < 4; c++) {
      sc[c] = (floatx4){0.f, 0.f, 0.f, 0.f};
      sc[c] = MFMA16(aq0, kf[2 * c], sc[c]);
      sc[c] = MFMA16(aq1, kf[2 * c + 1], sc[c]);
    }
    __builtin_amdgcn_s_setprio(0);

    float mt[4], al[4];
#pragma unroll
    for (int i = 0; i < 4; i++) {
      const int rowg = q0 + quad * 4 + i;
      float vmax = -INFINITY;
#pragma unroll
      for (int c = 0; c < 4; c++) {
        float v = sc[c][i] * 0.125f;
        if (mT && (k0 + 16 * c + lx) > rowg) v = -INFINITY;
        sc[c][i] = v;
        vmax = fmaxf(vmax, v);
      }
      mt[i] = vmax;
    }
#pragma unroll
    for (int i = 0; i < 4; i++) {
#pragma unroll
      for (int off = 8; off >= 1; off >>= 1)
        mt[i] = fmaxf(mt[i], __shfl_xor(mt[i], off));
      const float mn = fmaxf(m_i[i], mt[i]);
      al[i] = __expf(m_i[i] - mn);
      m_i[i] = mn;
      float s = 0.f;
#pragma unroll
      for (int c = 0; c < 4; c++) {
        float p = __expf(sc[c][i] - mn);
        Ps[w][quad * 4 + i][16 * c + lx] = f2bf(p);
        s += p;
      }
#pragma unroll
      for (int off = 8; off >= 1; off >>= 1) s += __shfl_xor(s, off);
      l_i[i] = l_i[i] * al[i] + s;
    }
#pragma unroll
    for (int c = 0; c < 4; c++)
#pragma unroll
      for (int i = 0; i < 4; i++) O[c][i] *= al[i];
    asm volatile("" ::: "memory");  // keep ds_reads below the ds_writes above
    const short8 pf0 = *(const short8*)&Ps[w][lx][quad * 8];
    const short8 pf1 = *(const short8*)&Ps[w][lx][32 + quad * 8];
    __builtin_amdgcn_s_setprio(1);
#pragma unroll
    for (int c = 0; c < 4; c++) {
      O[c] = MFMA16(pf0, vf[c],     O[c]);
      O[c] = MFMA16(pf1, vf[4 + c], O[c]);
    }
    __builtin_amdgcn_s_setprio(0);
  }

  // deposit per-wave state
  if (lx == 0) {
#pragma unroll
    for (int i = 0; i < 4; i++) {
      mS[w][quad * 4 + i] = m_i[i];
      lS[w][quad * 4 + i] = l_i[i];
    }
  }
#pragma unroll
  for (int c = 0; c < 4; c++)
#pragma unroll
    for (int i = 0; i < 4; i++) Os[w][quad * 4 + i][16 * c + lx] = O[c][i];

  // wave 0: logits for global pairs above the diagonal (lane l owns dim d=l)
  if (w == 0) {
#pragma unroll
    for (int p = 0; p < 3; p++) {
      const int R = (p == 0) ? R0 : (p == 1) ? R1 : R2;
      const int C = (p == 0) ? C0 : (p == 1) ? C1 : C2;
      const int act = (R >= q0 && R < q0 + 16 && C > R);
      float d = 0.f;
      if (act) {
        const int dd = l;
        const char* qa = (const char*)Qf + ((size_t)(b * 128 + (R >> 4))) * 2048 +
                         (dd >> 5) * 1024 + ((R & 15) + ((dd >> 3) & 3) * 16) * 16 + (dd & 7) * 2;
        const char* ka = (const char*)Kf + ((size_t)(b * 32 + (C >> 6))) * 8192 +
                         (((C >> 4) & 3) * 2 + (dd >> 5)) * 1024 +
                         ((C & 15) + ((dd >> 3) & 3) * 16) * 16 + (dd & 7) * 2;
        d = bf2f(*(const unsigned short*)qa) * bf2f(*(const unsigned short*)ka);
#pragma unroll
        for (int off = 32; off >= 1; off >>= 1) d += __shfl_xor(d, off);
        d *= 0.125f;
      }
      if (l == 0) { lgF[p] = act; lgS[p] = d; }
    }
  }
  __syncthreads();

  // merge the 4 wave states (+ pair fixups), normalize, store
  {
    const int row = tid >> 4;          // 0..15
    const int d0  = (tid & 15) * 4;    // 0..60
    const int Rs[3] = {R0, R1, R2};
    const int Cs3[3] = {C0, C1, C2};

    float mf = -INFINITY;
#pragma unroll
    for (int w4 = 0; w4 < 4; w4++) mf = fmaxf(mf, mS[w4][row]);
#pragma unroll
    for (int p = 0; p < 3; p++)
      if (lgF[p] && (Rs[p] - q0) == row) mf = fmaxf(mf, lgS[p]);

    float lf = 0.f;
    float o0 = 0.f, o1 = 0.f, o2 = 0.f, o3 = 0.f;
#pragma unroll
    for (int w4 = 0; w4 < 4; w4++) {
      const float a = __expf(mS[w4][row] - mf);
      lf += a * lS[w4][row];
      const float* op = &Os[w4][row][d0];
      o0 += a * op[0]; o1 += a * op[1]; o2 += a * op[2]; o3 += a * op[3];
    }
#pragma unroll
    for (int p = 0; p < 3; p++) {
      if (lgF[p] && (Rs[p] - q0) == row) {
        const float pe = __expf(lgS[p] - mf);
        lf += pe;
        const int C = Cs3[p];
        float vv[4];
#pragma unroll
        for (int j = 0; j < 4; j++) {
          const int dim = d0 + j;
          const char* va = (const char*)Vf + ((size_t)(b * 32 + (C >> 6))) * 8192 +
                           (((C >> 5) & 1) * 4 + (dim >> 4)) * 1024 +
                           ((dim & 15) + ((C >> 3) & 3) * 16) * 16 + (C & 7) * 2;
          vv[j] = bf2f(*(const unsigned short*)va);
        }
        o0 += pe * vv[0]; o1 += pe * vv[1]; o2 += pe * vv[2]; o3 += pe * vv[3];
      }
    }
    const float inv = 1.0f / lf;
    float4 r;
    r.x = o0 * inv; r.y = o1 * inv; r.z = o2 * inv; r.w = o3 * inv;
    *(float4*)(out + ((size_t)b * SEQ + q0 + row) * 64 + d0) = r;
  }
}

// ================================= launch =====================================
extern "C" void kernel_launch(void* const* d_in, const int* in_sizes, int n_in,
                              void* d_out, int out_size, void* d_ws,
                              size_t ws_size, hipStream_t stream) {
  const float* xq = (const float*)d_in[0];
  const float* xk = (const float*)d_in[1];
  const float* xv = (const float*)d_in[2];
  const float* Wq = (const float*)d_in[3];
  const float* bq = (const float*)d_in[4];
  const float* Wk = (const float*)d_in[5];
  const float* bk = (const float*)d_in[6];
  const float* Wv = (const float*)d_in[7];
  const float* bv = (const float*)d_in[8];
  float* out = (float*)d_out;

  // workspace (bf16): Qf 1MB, Kf 1MB, Vf 1MB, WTc 384KB (fragment-major layouts)
  unsigned short* Qf  = (unsigned short*)d_ws;
  unsigned short* Kf  = Qf + (size_t)NBATCH * SEQ * 64;
  unsigned short* Vf  = Kf + (size_t)NBATCH * SEQ * 64;
  unsigned short* WTc = Vf + (size_t)NBATCH * SEQ * 64;

  nprng::PCG64 g;
  nprng::pcg_seed_from_seedseq0(g);
  long long rows[3], cols[3];
  nprng::choice3_2048(g, rows);
  nprng::choice3_2048(g, cols);

  wtrans_kernel<<<96, 256, 0, stream>>>(Wq, Wk, Wv, WTc);

  proj_kernel<<<768, 256, 0, stream>>>(xq, xk, xv, WTc, bq, bk, bv, Qf, Kf, Vf);

  dim3 agrid(SEQ / 16, NBATCH);
  attn_kernel<<<agrid, 256, 0, stream>>>(
      Qf, Kf, Vf, out, (int)rows[0], (int)cols[0], (int)rows[1], (int)cols[1],
      (int)rows[2], (int)cols[2]);
}

// Round 5
// 152.979 us; speedup vs baseline: 1.0997x; 1.0132x over previous
//
#include <hip/hip_runtime.h>
#include <cstdint>
#include <cstddef>
#include <math.h>

#define SEQ    2048
#define NBATCH 4
#define DIN    1024
#define DH     64

typedef __attribute__((ext_vector_type(8))) short  short8;   // 8 x bf16 (4 VGPRs)
typedef __attribute__((ext_vector_type(4))) float  floatx4;  // MFMA C/D

#define MFMA16(a, b, c) __builtin_amdgcn_mfma_f32_16x16x32_bf16((a), (b), (c), 0, 0, 0)

__device__ __forceinline__ unsigned short f2bf(float x) {
  unsigned u = __float_as_uint(x);
  return (unsigned short)((u + 0x8000u) >> 16);   // round-half-up; values finite
}
__device__ __forceinline__ float bf2f(unsigned short h) {
  return __uint_as_float(((unsigned)h) << 16);
}

// async global->LDS DMA, width 16: deposits at lds_base + lane*16.
__device__ __forceinline__ void async_cp16(const void* g, void* l) {
  __builtin_amdgcn_global_load_lds(
      (const __attribute__((address_space(1))) void*)g,
      (__attribute__((address_space(3))) void*)l, 16, 0, 0);
}

// volatile-asm W-fragment load: ordered among volatile asms, cannot be sunk.
template <int OFF>
__device__ __forceinline__ void gldw(short8 &d, unsigned long long a) {
  asm volatile("global_load_dwordx4 %0, %1, off offset:%2"
               : "=v"(d) : "v"(a), "n"(OFF));
}
#define WAITV(N) asm volatile("s_waitcnt vmcnt(" #N ")" ::: "memory")
#define SB()     __builtin_amdgcn_sched_barrier(0)
#define BAR()    __builtin_amdgcn_s_barrier()

// inline-asm LDS read: invisible to the compiler's DMA-alias tracking, so no
// conservative vmcnt(0) can be attached to it (round-4 suspect #1).
#define DSR(dst, ra, OFF)                                                      \
  asm volatile("ds_read_b128 %0, %1 offset:%2" : "=v"(dst) : "v"(ra), "n"(OFF))

// ======================= host-side numpy RNG replication =======================
namespace nprng {

struct PCG64 {
  __uint128_t state, inc;
  bool has_uint32;
  uint32_t uinteger;
};

static inline void pcg_step(PCG64 &g) {
  const __uint128_t MULT =
      (((__uint128_t)0x2360ed051fc65da4ULL) << 64) | 0x4385df649fccf645ULL;
  g.state = g.state * MULT + g.inc;
}

static inline uint64_t pcg_output(const PCG64 &g) {
  uint64_t hi = (uint64_t)(g.state >> 64);
  uint64_t lo = (uint64_t)g.state;
  uint64_t x = hi ^ lo;
  unsigned rot = (unsigned)(g.state >> 122) & 63u;
  return (x >> rot) | (x << ((64u - rot) & 63u));
}

static inline uint64_t pcg_next64(PCG64 &g) { pcg_step(g); return pcg_output(g); }

static inline uint32_t pcg_next32(PCG64 &g) {
  if (g.has_uint32) { g.has_uint32 = false; return g.uinteger; }
  uint64_t n = pcg_next64(g);
  g.has_uint32 = true;
  g.uinteger = (uint32_t)(n >> 32);
  return (uint32_t)(n & 0xffffffffu);
}

static inline void pcg_seed_from_seedseq0(PCG64 &g) {
  const uint32_t MULT_A = 0x931e8875u;
  const uint32_t MULT_B = 0x58f38dedu;
  const uint32_t MIX_L  = 0xca01f9ddu;
  const uint32_t MIX_R  = 0x4973f715u;
  uint32_t hc = 0x43b0d7e5u;  // INIT_A
  uint32_t pool[4];
  for (int i = 0; i < 4; i++) {
    uint32_t v = 0u;
    v ^= hc; hc *= MULT_A; v *= hc; v ^= v >> 16;
    pool[i] = v;
  }
  for (int is = 0; is < 4; is++) {
    for (int id = 0; id < 4; id++) {
      if (is == id) continue;
      uint32_t h = pool[is];
      h ^= hc; hc *= MULT_A; h *= hc; h ^= h >> 16;
      uint32_t r = (pool[id] * MIX_L) ^ (h * MIX_R);
      r ^= r >> 16;
      pool[id] = r;
    }
  }
  uint32_t hb = 0x8b51f9ddu;  // INIT_B
  uint32_t w[8];
  for (int i = 0; i < 8; i++) {
    uint32_t v = pool[i & 3];
    v ^= hb; hb *= MULT_B; v *= hb; v ^= v >> 16;
    w[i] = v;
  }
  uint64_t sv[4];
  for (int k = 0; k < 4; k++)
    sv[k] = (uint64_t)w[2 * k] | ((uint64_t)w[2 * k + 1] << 32);
  __uint128_t initstate = (((__uint128_t)sv[0]) << 64) | sv[1];
  __uint128_t initseq   = (((__uint128_t)sv[2]) << 64) | sv[3];
  g.state = 0; g.inc = (initseq << 1) | 1;
  pcg_step(g);
  g.state += initstate;
  pcg_step(g);
  g.has_uint32 = false; g.uinteger = 0;
}

static inline uint32_t bounded32(PCG64 &g, uint32_t rng /*inclusive max*/) {
  if (rng == 0) return 0;
  const uint32_t rng_excl = rng + 1u;
  uint64_t m = (uint64_t)pcg_next32(g) * (uint64_t)rng_excl;
  uint32_t leftover = (uint32_t)m;
  if (leftover < rng_excl) {
    const uint32_t threshold = (uint32_t)(0xffffffffu - rng) % rng_excl;
    while (leftover < threshold) {
      m = (uint64_t)pcg_next32(g) * (uint64_t)rng_excl;
      leftover = (uint32_t)m;
    }
  }
  return (uint32_t)(m >> 32);
}

static inline void choice3_2048(PCG64 &g, long long idx[3]) {
  const int pop = 2048, sz = 3;
  uint64_t hs[4] = { (uint64_t)-1, (uint64_t)-1, (uint64_t)-1, (uint64_t)-1 };
  const uint64_t mask = 3;
  for (int j = pop - sz; j < pop; j++) {
    uint64_t val = (uint64_t)bounded32(g, (uint32_t)j);
    uint64_t loc = val & mask;
    while (hs[loc] != (uint64_t)-1 && hs[loc] != val) loc = (loc + 1) & mask;
    if (hs[loc] == (uint64_t)-1) {
      hs[loc] = val;
      idx[j - pop + sz] = (long long)val;
    } else {
      loc = (uint64_t)j & mask;
      while (hs[loc] != (uint64_t)-1) loc = (loc + 1) & mask;
      hs[loc] = (uint64_t)j;
      idx[j - pop + sz] = (long long)j;
    }
  }
  for (int i = 2; i >= 1; i--) {
    uint32_t j = bounded32(g, (uint32_t)i);
    long long t = idx[j]; idx[j] = idx[i]; idx[i] = t;
  }
}

}  // namespace nprng

// ==================== kernel 0: W -> fragment-major bf16 WTc ==================
// WTc layout (short8 units): u = ((((p*8+kc)*2 + nch)*4 + ks)*2 + f)*64 + l
// unit content, element j: W[(kc*128 + ks*32 + (l>>4)*8 + j)*64 + nch*32 + f*16 + (l&15)]
// i.e. exactly the MFMA B-fragment wave (col-half nch) lane l needs for (kc,ks,f).
__global__ __launch_bounds__(256) void wtrans_kernel(
    const float* __restrict__ Wq, const float* __restrict__ Wk,
    const float* __restrict__ Wv, unsigned short* __restrict__ WTc) {
  const int u = blockIdx.x * 256 + threadIdx.x;   // 0 .. 24575 short8 units
  const int l   = u & 63;
  const int fi  = (u >> 6) & 7;    // fi = ks*2 + f
  const int nch = (u >> 9) & 1;
  const int kc  = (u >> 10) & 7;
  const int p   = u >> 13;         // 0..2
  const int f   = fi & 1;
  const int ks  = fi >> 1;
  const float* W = (p == 0) ? Wq : (p == 1) ? Wk : Wv;
  const int n  = nch * 32 + f * 16 + (l & 15);
  const int k0 = kc * 128 + ks * 32 + ((l >> 4) * 8);
  short8 v;
#pragma unroll
  for (int j = 0; j < 8; j++) v[j] = (short)f2bf(W[(size_t)(k0 + j) * 64 + n]);
  *((short8*)WTc + u) = v;
}

// ======== projections: width-16 swizzled DMA, tri-buffer, asm ds_read =========
// grid 768 x 256 thr (4 waves). Block = 32 rows; wave w: row-half (w&1),
// col-half (w>>1). K=1024 in 8 chunks of 128. X: LINEAR [32][128]f32 LDS tile
// staged by 16 width-16 global_load_lds per block per chunk (4/wave, 4x fewer
// ops than round 4's width-4), TRI-buffered (2-deep lookahead). Bank conflicts
// killed by the T2 both-sides XOR swizzle: X[row][u] lives at LDS[row][u^(row&7)]
// (16B units) -- the DMA dest is linear, the per-lane GLOBAL source address is
// pre-swizzled (rule 21 / m173), and the read address folds the same XOR.
// Reads are inline-asm ds_read_b128 + manual lgkmcnt(0)+sched_barrier(0), so
// the compiler cannot attach a conservative vmcnt(0) to them (round-4 suspect).
// W: volatile-asm reg loads from L2-resident WTc, double-buffered. Counted
// vmcnt: steady 16, tail 12 -> 0; never a mid-loop drain. LDS 48 KB, 3 blk/CU.
__global__ __launch_bounds__(256, 3) void proj_kernel(
    const float* __restrict__ xq, const float* __restrict__ xk,
    const float* __restrict__ xv, const unsigned short* __restrict__ WTc,
    const float* __restrict__ bq, const float* __restrict__ bk,
    const float* __restrict__ bv,
    unsigned short* __restrict__ Qf, unsigned short* __restrict__ Kf,
    unsigned short* __restrict__ Vf) {
  const int m0g  = blockIdx.x * 32;        // 0..24544
  const int proj = m0g >> 13;              // 0,1,2
  const int m0   = m0g & 8191;             // row within proj
  const float* X    = (proj == 0) ? xq : (proj == 1) ? xk : xv;
  const float* bias = (proj == 0) ? bq : (proj == 1) ? bk : bv;

  const int tid  = threadIdx.x;
  const int w    = tid >> 6;
  const int l    = tid & 63;
  const int quad = l >> 4;
  const int lx   = l & 15;
  const int mr   = (w & 1) * 16;           // wave's row half
  const int nc   = (w >> 1) * 32;          // wave's col half

  __shared__ __align__(16) char LDSbuf[3 * 16384];   // 3 x [32][128] f32

  const float* Xblk = X + (size_t)m0 * DIN;

  // per-lane pre-swizzled global X source for DMA op i (i=0..3):
  //   row = 8w + 2i + (l>>5); unit_dst = l&31; unit_src = unit_dst ^ (row&7)
  const char *ga0, *ga1, *ga2, *ga3;
  {
    const int lh = l >> 5, lu = l & 31;
#define GAX(i) ((const char*)(Xblk + (size_t)(8 * w + 2 * (i) + lh) * DIN) +    \
                (size_t)((lu ^ ((2 * (i) + lh) & 7)) << 4))
    ga0 = GAX(0); ga1 = GAX(1); ga2 = GAX(2); ga3 = GAX(3);
#undef GAX
  }

  // swizzled per-lane LDS read addresses (d=0,1); chunk/ks go in offset: imm.
  //   byte = row*512 + (ks*8 + ((quad*2+d)^(lx&7)))*16, row = mr+lx
  const unsigned ldsb =
      (unsigned)(size_t)(__attribute__((address_space(3))) char*)LDSbuf;
  const unsigned ra0 = ldsb + (mr + lx) * 512 + (((quad * 2 + 0) ^ (lx & 7)) << 4);
  const unsigned ra1 = ldsb + (mr + lx) * 512 + (((quad * 2 + 1) ^ (lx & 7)) << 4);

  const unsigned long long wab =
      (unsigned long long)(const void*)((const short8*)WTc +
                                        ((size_t)(proj * 16 + (w >> 1))) * 512 + l);

  floatx4 acc0 = {0.f, 0.f, 0.f, 0.f}, acc1 = acc0;
  short8  wa[8], wb[8];
  floatx4 x0, x1, x2, x3, x4, x5, x6, x7;

#define STAGEX(KC, XB)                                                         \
  async_cp16(ga0 + (KC) * 512, LDSbuf + (XB) * 16384 + w * 4096 + 0);          \
  async_cp16(ga1 + (KC) * 512, LDSbuf + (XB) * 16384 + w * 4096 + 1024);       \
  async_cp16(ga2 + (KC) * 512, LDSbuf + (XB) * 16384 + w * 4096 + 2048);       \
  async_cp16(ga3 + (KC) * 512, LDSbuf + (XB) * 16384 + w * 4096 + 3072);

#define STAGEW(KC, WBUF)                                                       \
  { const unsigned long long p0 = wab + (KC) * 16384ull;                       \
    const unsigned long long p1 = p0 + 4096ull;                                \
    gldw<   0>(WBUF[0], p0); gldw<1024>(WBUF[1], p0);                          \
    gldw<2048>(WBUF[2], p0); gldw<3072>(WBUF[3], p0);                          \
    gldw<   0>(WBUF[4], p1); gldw<1024>(WBUF[5], p1);                          \
    gldw<2048>(WBUF[6], p1); gldw<3072>(WBUF[7], p1); }

#define READX(XB)                                                              \
  DSR(x0, ra0, (XB) * 16384 + 0);   DSR(x1, ra1, (XB) * 16384 + 0);            \
  DSR(x2, ra0, (XB) * 16384 + 128); DSR(x3, ra1, (XB) * 16384 + 128);          \
  DSR(x4, ra0, (XB) * 16384 + 256); DSR(x5, ra1, (XB) * 16384 + 256);          \
  DSR(x6, ra0, (XB) * 16384 + 384); DSR(x7, ra1, (XB) * 16384 + 384);          \
  asm volatile("s_waitcnt lgkmcnt(0)" ::: "memory");                           \
  __builtin_amdgcn_sched_barrier(0);

#define CVTM(f0, f1, w0, w1)                                                   \
  { short8 a_;                                                                 \
    a_[0] = f2bf(f0[0]); a_[1] = f2bf(f0[1]); a_[2] = f2bf(f0[2]); a_[3] = f2bf(f0[3]); \
    a_[4] = f2bf(f1[0]); a_[5] = f2bf(f1[1]); a_[6] = f2bf(f1[2]); a_[7] = f2bf(f1[3]); \
    acc0 = MFMA16(a_, w0, acc0); acc1 = MFMA16(a_, w1, acc1); }

#define DOMFMA(WBUF)                                                           \
  CVTM(x0, x1, WBUF[0], WBUF[1]); CVTM(x2, x3, WBUF[2], WBUF[3]);              \
  CVTM(x4, x5, WBUF[4], WBUF[5]); CVTM(x6, x7, WBUF[6], WBUF[7]);

  // prologue: X chunks 0..2 + W chunks 0..1 in flight (28 VMEM ops)
  STAGEX(0, 0); STAGEW(0, wa); STAGEX(1, 1); STAGEW(1, wb); STAGEX(2, 2);

  // k=0..7; buffers k%3; W regs k&1; issue SW(k+2), SX(k+3) after the
  // post-read barrier (all waves done reading buf k%3 = dest of SX(k+3)).
  WAITV(16); SB(); BAR(); READX(0); BAR(); DOMFMA(wa); STAGEW(2, wa); STAGEX(3, 0);
  WAITV(16); SB(); BAR(); READX(1); BAR(); DOMFMA(wb); STAGEW(3, wb); STAGEX(4, 1);
  WAITV(16); SB(); BAR(); READX(2); BAR(); DOMFMA(wa); STAGEW(4, wa); STAGEX(5, 2);
  WAITV(16); SB(); BAR(); READX(0); BAR(); DOMFMA(wb); STAGEW(5, wb); STAGEX(6, 0);
  WAITV(16); SB(); BAR(); READX(1); BAR(); DOMFMA(wa); STAGEW(6, wa); STAGEX(7, 1);
  WAITV(16); SB(); BAR(); READX(2); BAR(); DOMFMA(wb); STAGEW(7, wb);
  WAITV(12); SB(); BAR(); READX(0); BAR(); DOMFMA(wa);
  WAITV(0);  SB(); BAR(); READX(1); BAR(); DOMFMA(wb);

#undef STAGEX
#undef STAGEW
#undef READX
#undef CVTM
#undef DOMFMA

  // ---- epilogue: stage 32x64 tile (+bias) in LDS (aliases buffer 0; its last
  // reader was chunk 6, closed by that chunk's post-read barrier), emit frags.
  float (*Cs)[68] = (float(*)[68])LDSbuf;  // 32 x 68 f32 = 8704 B
  const float bb0 = bias[nc + lx], bb1 = bias[nc + 16 + lx];
#pragma unroll
  for (int i = 0; i < 4; i++) {
    Cs[mr + quad * 4 + i][nc + lx]      = acc0[i] + bb0;
    Cs[mr + quad * 4 + i][nc + 16 + lx] = acc1[i] + bb1;
  }
  __syncthreads();

  const int bq_ = m0 >> 11;                // batch
  const int s0  = m0 & 2047;               // seq offset within batch
  if (proj == 0) {
    // Q: two 16-row tiles, frag s, lane ll
    const int ti = tid >> 7, s = (tid >> 6) & 1, ll = tid & 63;
    const int lxx = ll & 15, qq = ll >> 4;
    short8 v;
#pragma unroll
    for (int j = 0; j < 8; j++) v[j] = (short)f2bf(Cs[ti * 16 + lxx][s * 32 + qq * 8 + j]);
    char* dst = (char*)Qf + ((size_t)(bq_ * 128 + (s0 >> 4) + ti)) * 2048 + s * 1024 + ll * 16;
    *(short8*)dst = v;
  } else if (proj == 1) {
    // K: half of a 64-row tile -> frags (c0+ci, s)
    const int ci = tid >> 7, s = (tid >> 6) & 1, ll = tid & 63;
    const int lxx = ll & 15, qq = ll >> 4;
    const int c = ((s0 >> 4) & 3) + ci;
    short8 v;
#pragma unroll
    for (int j = 0; j < 8; j++) v[j] = (short)f2bf(Cs[ci * 16 + lxx][s * 32 + qq * 8 + j]);
    char* dst = (char*)Kf + ((size_t)(bq_ * 32 + (s0 >> 6))) * 8192 + (c * 2 + s) * 1024 + ll * 16;
    *(short8*)dst = v;
  } else {
    // V: s-half of a 64-row tile -> frags (sh, c=0..3); lane gathers 8 seq rows
    const int c = tid >> 6, ll = tid & 63;
    const int lxx = ll & 15, qq = ll >> 4;
    const int sh = (s0 >> 5) & 1;
    short8 v;
#pragma unroll
    for (int j = 0; j < 8; j++) v[j] = (short)f2bf(Cs[qq * 8 + j][c * 16 + lxx]);
    char* dst = (char*)Vf + ((size_t)(bq_ * 32 + (s0 >> 6))) * 8192 + (sh * 4 + c) * 1024 + ll * 16;
    *(short8*)dst = v;
  }
}

// ============ flash attention: fragment-major direct loads, 1 barrier =========
// grid (128, 4), 256 threads (4 waves). Block = 16 q-rows; wave w processes
// key-tiles t = w, w+4, ... with independent online-softmax state; merged once.
// All Q/K/V fragment loads are per-wave LINEAR global reads (chunk + lane*16):
// perfect coalescing, no LDS staging, no barriers, no bank conflicts.
__global__ __launch_bounds__(256, 2) void attn_kernel(
    const unsigned short* __restrict__ Qf, const unsigned short* __restrict__ Kf,
    const unsigned short* __restrict__ Vf, float* __restrict__ out,
    int R0, int C0, int R1, int C1, int R2, int C2) {
  const int b    = blockIdx.y;
  const int bx   = blockIdx.x;
  const int qi   = (bx & 1) ? (127 - (bx >> 1)) : (bx >> 1);  // heavy/light pairing
  const int q0   = qi * 16;
  const int tid  = threadIdx.x;
  const int w    = tid >> 6;
  const int l    = tid & 63;
  const int quad = l >> 4;
  const int lx   = l & 15;

  __shared__ unsigned short Ps[4][16][72];
  __shared__ float Os[4][16][64];
  __shared__ float mS[4][16], lS[4][16];
  __shared__ float lgS[3];
  __shared__ int   lgF[3];

  const char* Qc = (const char*)Qf + ((size_t)(b * 128 + qi)) * 2048 + l * 16;
  const short8 aq0 = *(const short8*)Qc;
  const short8 aq1 = *(const short8*)(Qc + 1024);

  floatx4 O[4];
  float m_i[4], l_i[4];
#pragma unroll
  for (int c = 0; c < 4; c++) O[c] = (floatx4){0.f, 0.f, 0.f, 0.f};
#pragma unroll
  for (int i = 0; i < 4; i++) { m_i[i] = -INFINITY; l_i[i] = 0.f; }

  const int T = (q0 + 79) >> 6;   // key-tiles needed (64 keys each)

  for (int t = w; t < T; t += 4) {
    const int k0 = t << 6;
    const bool mT = (t == T - 1);

    const char* Kc = (const char*)Kf + ((size_t)(b * 32 + t)) * 8192 + l * 16;
    const char* Vc = (const char*)Vf + ((size_t)(b * 32 + t)) * 8192 + l * 16;
    short8 kf[8], vf[8];
#pragma unroll
    for (int f = 0; f < 8; f++) {
      kf[f] = *(const short8*)(Kc + f * 1024);
      vf[f] = *(const short8*)(Vc + f * 1024);
    }

    floatx4 sc[4];
    __builtin_amdgcn_s_setprio(1);
#pragma unroll
    for (int c = 0; c < 4; c++) {
      sc[c] = (floatx4){0.f, 0.f, 0.f, 0.f};
      sc[c] = MFMA16(aq0, kf[2 * c], sc[c]);
      sc[c] = MFMA16(aq1, kf[2 * c + 1], sc[c]);
    }
    __builtin_amdgcn_s_setprio(0);

    float mt[4], al[4];
#pragma unroll
    for (int i = 0; i < 4; i++) {
      const int rowg = q0 + quad * 4 + i;
      float vmax = -INFINITY;
#pragma unroll
      for (int c = 0; c < 4; c++) {
        float v = sc[c][i] * 0.125f;
        if (mT && (k0 + 16 * c + lx) > rowg) v = -INFINITY;
        sc[c][i] = v;
        vmax = fmaxf(vmax, v);
      }
      mt[i] = vmax;
    }
#pragma unroll
    for (int i = 0; i < 4; i++) {
#pragma unroll
      for (int off = 8; off >= 1; off >>= 1)
        mt[i] = fmaxf(mt[i], __shfl_xor(mt[i], off));
      const float mn = fmaxf(m_i[i], mt[i]);
      al[i] = __expf(m_i[i] - mn);
      m_i[i] = mn;
      float s = 0.f;
#pragma unroll
      for (int c = 0; c < 4; c++) {
        float p = __expf(sc[c][i] - mn);
        Ps[w][quad * 4 + i][16 * c + lx] = f2bf(p);
        s += p;
      }
#pragma unroll
      for (int off = 8; off >= 1; off >>= 1) s += __shfl_xor(s, off);
      l_i[i] = l_i[i] * al[i] + s;
    }
#pragma unroll
    for (int c = 0; c < 4; c++)
#pragma unroll
      for (int i = 0; i < 4; i++) O[c][i] *= al[i];
    asm volatile("" ::: "memory");  // keep ds_reads below the ds_writes above
    const short8 pf0 = *(const short8*)&Ps[w][lx][quad * 8];
    const short8 pf1 = *(const short8*)&Ps[w][lx][32 + quad * 8];
    __builtin_amdgcn_s_setprio(1);
#pragma unroll
    for (int c = 0; c < 4; c++) {
      O[c] = MFMA16(pf0, vf[c],     O[c]);
      O[c] = MFMA16(pf1, vf[4 + c], O[c]);
    }
    __builtin_amdgcn_s_setprio(0);
  }

  // deposit per-wave state
  if (lx == 0) {
#pragma unroll
    for (int i = 0; i < 4; i++) {
      mS[w][quad * 4 + i] = m_i[i];
      lS[w][quad * 4 + i] = l_i[i];
    }
  }
#pragma unroll
  for (int c = 0; c < 4; c++)
#pragma unroll
    for (int i = 0; i < 4; i++) Os[w][quad * 4 + i][16 * c + lx] = O[c][i];

  // wave 0: logits for global pairs above the diagonal (lane l owns dim d=l)
  if (w == 0) {
#pragma unroll
    for (int p = 0; p < 3; p++) {
      const int R = (p == 0) ? R0 : (p == 1) ? R1 : R2;
      const int C = (p == 0) ? C0 : (p == 1) ? C1 : C2;
      const int act = (R >= q0 && R < q0 + 16 && C > R);
      float d = 0.f;
      if (act) {
        const int dd = l;
        const char* qa = (const char*)Qf + ((size_t)(b * 128 + (R >> 4))) * 2048 +
                         (dd >> 5) * 1024 + ((R & 15) + ((dd >> 3) & 3) * 16) * 16 + (dd & 7) * 2;
        const char* ka = (const char*)Kf + ((size_t)(b * 32 + (C >> 6))) * 8192 +
                         (((C >> 4) & 3) * 2 + (dd >> 5)) * 1024 +
                         ((C & 15) + ((dd >> 3) & 3) * 16) * 16 + (dd & 7) * 2;
        d = bf2f(*(const unsigned short*)qa) * bf2f(*(const unsigned short*)ka);
#pragma unroll
        for (int off = 32; off >= 1; off >>= 1) d += __shfl_xor(d, off);
        d *= 0.125f;
      }
      if (l == 0) { lgF[p] = act; lgS[p] = d; }
    }
  }
  __syncthreads();

  // merge the 4 wave states (+ pair fixups), normalize, store
  {
    const int row = tid >> 4;          // 0..15
    const int d0  = (tid & 15) * 4;    // 0..60
    const int Rs[3] = {R0, R1, R2};
    const int Cs3[3] = {C0, C1, C2};

    float mf = -INFINITY;
#pragma unroll
    for (int w4 = 0; w4 < 4; w4++) mf = fmaxf(mf, mS[w4][row]);
#pragma unroll
    for (int p = 0; p < 3; p++)
      if (lgF[p] && (Rs[p] - q0) == row) mf = fmaxf(mf, lgS[p]);

    float lf = 0.f;
    float o0 = 0.f, o1 = 0.f, o2 = 0.f, o3 = 0.f;
#pragma unroll
    for (int w4 = 0; w4 < 4; w4++) {
      const float a = __expf(mS[w4][row] - mf);
      lf += a * lS[w4][row];
      const float* op = &Os[w4][row][d0];
      o0 += a * op[0]; o1 += a * op[1]; o2 += a * op[2]; o3 += a * op[3];
    }
#pragma unroll
    for (int p = 0; p < 3; p++) {
      if (lgF[p] && (Rs[p] - q0) == row) {
        const float pe = __expf(lgS[p] - mf);
        lf += pe;
        const int C = Cs3[p];
        float vv[4];
#pragma unroll
        for (int j = 0; j < 4; j++) {
          const int dim = d0 + j;
          const char* va = (const char*)Vf + ((size_t)(b * 32 + (C >> 6))) * 8192 +
                           (((C >> 5) & 1) * 4 + (dim >> 4)) * 1024 +
                           ((dim & 15) + ((C >> 3) & 3) * 16) * 16 + (C & 7) * 2;
          vv[j] = bf2f(*(const unsigned short*)va);
        }
        o0 += pe * vv[0]; o1 += pe * vv[1]; o2 += pe * vv[2]; o3 += pe * vv[3];
      }
    }
    const float inv = 1.0f / lf;
    float4 r;
    r.x = o0 * inv; r.y = o1 * inv; r.z = o2 * inv; r.w = o3 * inv;
    *(float4*)(out + ((size_t)b * SEQ + q0 + row) * 64 + d0) = r;
  }
}

// ================================= launch =====================================
extern "C" void kernel_launch(void* const* d_in, const int* in_sizes, int n_in,
                              void* d_out, int out_size, void* d_ws,
                              size_t ws_size, hipStream_t stream) {
  const float* xq = (const float*)d_in[0];
  const float* xk = (const float*)d_in[1];
  const float* xv = (const float*)d_in[2];
  const float* Wq = (const float*)d_in[3];
  const float* bq = (const float*)d_in[4];
  const float* Wk = (const float*)d_in[5];
  const float* bk = (const float*)d_in[6];
  const float* Wv = (const float*)d_in[7];
  const float* bv = (const float*)d_in[8];
  float* out = (float*)d_out;

  // workspace (bf16): Qf 1MB, Kf 1MB, Vf 1MB, WTc 384KB (fragment-major layouts)
  unsigned short* Qf  = (unsigned short*)d_ws;
  unsigned short* Kf  = Qf + (size_t)NBATCH * SEQ * 64;
  unsigned short* Vf  = Kf + (size_t)NBATCH * SEQ * 64;
  unsigned short* WTc = Vf + (size_t)NBATCH * SEQ * 64;

  nprng::PCG64 g;
  nprng::pcg_seed_from_seedseq0(g);
  long long rows[3], cols[3];
  nprng::choice3_2048(g, rows);
  nprng::choice3_2048(g, cols);

  wtrans_kernel<<<96, 256, 0, stream>>>(Wq, Wk, Wv, WTc);

  proj_kernel<<<768, 256, 0, stream>>>(xq, xk, xv, WTc, bq, bk, bv, Qf, Kf, Vf);

  dim3 agrid(SEQ / 16, NBATCH);
  attn_kernel<<<agrid, 256, 0, stream>>>(
      Qf, Kf, Vf, out, (int)rows[0], (int)cols[0], (int)rows[1], (int)cols[1],
      (int)rows[2], (int)cols[2]);
}